// Round 12
// baseline (359.369 us; speedup 1.0000x reference)
//
#include <hip/hip_runtime.h>

#define SQ 4096
#define SKV 1024
#define BATCH 4
#define NH 8
#define DH 64
#define QD 1024
#define CD 768
#define INNER 512

typedef _Float16 half8 __attribute__((ext_vector_type(8)));
typedef _Float16 half4v __attribute__((ext_vector_type(4)));
typedef float floatx4 __attribute__((ext_vector_type(4)));
typedef float f32x16 __attribute__((ext_vector_type(16)));
typedef unsigned int uint4v __attribute__((ext_vector_type(4)));

#define MFMA16(a, b, c) __builtin_amdgcn_mfma_f32_16x16x32_f16(a, b, c, 0, 0, 0)
#define MFMA32(a, b, c) __builtin_amdgcn_mfma_f32_32x32x16_f16(a, b, c, 0, 0, 0)

// v_permlane32_swap_b32: a' = {a.lo31, b.lo31}, b' = {a.hi31, b.hi31}
#define PLSWAP(a, b) asm("v_permlane32_swap_b32 %0, %1" : "+v"(a), "+v"(b))

// async global->LDS, 16B per lane; LDS dest = wave-uniform base + lane*16
#define GLD16(gptr, lptr)                                                            \
  __builtin_amdgcn_global_load_lds(                                                  \
      (const __attribute__((address_space(1))) unsigned int*)(const void*)(gptr),    \
      (__attribute__((address_space(3))) unsigned int*)(void*)(lptr), 16, 0, 0)

// ---------------------------------------------------------------- weight transposes
// 4 weight transposes in one launch; z selects the matrix. (r0-green form.)
// src [R,C] fp32 -> dst [C,R] fp16.
__global__ __launch_bounds__(256) void transpose_all(const float* __restrict__ Wq,
                                                     const float* __restrict__ Wk,
                                                     const float* __restrict__ Wv,
                                                     const float* __restrict__ Wo,
                                                     _Float16* __restrict__ wqt,
                                                     _Float16* __restrict__ wkvt,
                                                     _Float16* __restrict__ wot) {
  __shared__ float tile[32][33];
  const int z = blockIdx.z;
  const float* src; _Float16* dst; int R, C;
  if (z == 0)      { src = Wq; dst = wqt;                        R = QD;    C = INNER; }
  else if (z == 1) { src = Wk; dst = wkvt;                       R = CD;    C = INNER; }
  else if (z == 2) { src = Wv; dst = wkvt + (size_t)INNER * CD;  R = CD;    C = INNER; }
  else             { src = Wo; dst = wot;                        R = INNER; C = QD;   }
  const int c0 = blockIdx.x * 32, r0 = blockIdx.y * 32;
  if (c0 >= C || r0 >= R) return;
  const int tx = threadIdx.x & 31, ty = threadIdx.x >> 5;
#pragma unroll
  for (int i = 0; i < 32; i += 8)
    tile[ty + i][tx] = src[(size_t)(r0 + ty + i) * C + c0 + tx];
  __syncthreads();
#pragma unroll
  for (int i = 0; i < 32; i += 8)
    dst[(size_t)(c0 + ty + i) * R + r0 + tx] = (_Float16)tile[tx][ty + i];
}

// ---------------------------------------------------------------- no-LDS reg GEMM
// C[M,N] = A[M,K] @ B[K,N], B transposed (Bt[N,K], fp16 row-major).
// A row-major: fp32 if AF32 (loaded to regs, converted RTNE) else fp16.
// Tile 128x128, 4 waves (2x2 of 64x64), each wave loads its OWN fragments straight
// from global to registers — NO LDS, NO __syncthreads. Rationale (r10/r11 PMC):
// the LDS dbuf loop's __syncthreads compiles to s_waitcnt vmcnt(0)+s_barrier (full
// drain) -> prefetch coverage capped at one ~300cyc compute phase vs 200-900cyc
// latency -> 5250cyc/k-step, all pipes <26%. Removing the barrier lets the compiler
// emit COUNTED vmcnt waits, #pragma unroll 2 (K compile-time) gives cross-step
// prefetch, and 12 independent waves/CU hide the rest. Redundancy (A x2 waves,
// B x2) is served by L1 broadcast + XCD-local L2 (panels L2-hot; HBM was 13%).
// MODE 2: fp32 + bias. MODE 3: fp16 out scaled by 0.125*log2(e).
// MODE 4: merged k/v epilogue — n<512 -> kh row-major [M,512]; n>=512 -> vT scatter.
template <int MODE, int AF32, int N, int K>
__device__ __forceinline__ void gemm_reg(const void* __restrict__ Aany,
                                         const _Float16* __restrict__ Bt,
                                         void* __restrict__ Cout,
                                         void* __restrict__ Cout2,
                                         const float* __restrict__ bias,
                                         int bx, int by) {
  const int tid = threadIdx.x;
  const int wave = tid >> 6, lane = tid & 63;
  const int quad = lane >> 4, l16 = lane & 15;
  const int wm = (wave >> 1) * 64, wn = (wave & 1) * 64;
  const size_t n0 = (size_t)bx * 128, m0 = (size_t)by * 128;

  floatx4 acc[4][4] = {};

  // per-lane fragment bases: row = (m0|n0) + (wm|wn) + frag*16 + l16, k = k0 + quad*8
  const float* a32 = (const float*)Aany + (m0 + wm + l16) * (size_t)K + quad * 8;
  const _Float16* a16 = (const _Float16*)Aany + (m0 + wm + l16) * (size_t)K + quad * 8;
  const _Float16* bg = Bt + (n0 + wn + l16) * (size_t)K + quad * 8;

#pragma unroll 2
  for (int k0 = 0; k0 < K; k0 += 32) {
    half8 af[4], bf[4];
#pragma unroll
    for (int nt = 0; nt < 4; ++nt)
      bf[nt] = *(const half8*)(bg + (size_t)nt * 16 * K + k0);
#pragma unroll
    for (int mt = 0; mt < 4; ++mt) {
      if (AF32) {
        floatx4 x0 = *(const floatx4*)(a32 + (size_t)mt * 16 * K + k0);
        floatx4 x1 = *(const floatx4*)(a32 + (size_t)mt * 16 * K + k0 + 4);
        half8 tt;
#pragma unroll
        for (int i = 0; i < 4; ++i) { tt[i] = (_Float16)x0[i]; tt[4 + i] = (_Float16)x1[i]; }
        af[mt] = tt;
      } else {
        af[mt] = *(const half8*)(a16 + (size_t)mt * 16 * K + k0);
      }
    }
#pragma unroll
    for (int mt = 0; mt < 4; ++mt)
#pragma unroll
      for (int nt = 0; nt < 4; ++nt)
        acc[mt][nt] = MFMA16(af[mt], bf[nt], acc[mt][nt]);
  }

  // epilogue: C/D layout row = quad*4+r, col = l16  (r8/r10-green forms)
  if (MODE == 3) {
    _Float16* C = (_Float16*)Cout;
    // fold softmax scale (1/8) and log2(e) into Q so attention uses exp2
    const float sc = 0.125f * 1.44269504088896f;
#pragma unroll
    for (int mt = 0; mt < 4; ++mt) {
      const size_t row = m0 + wm + mt * 16 + quad * 4;
#pragma unroll
      for (int nt = 0; nt < 4; ++nt) {
        const size_t col = n0 + wn + nt * 16 + l16;
#pragma unroll
        for (int r = 0; r < 4; ++r)
          C[(row + r) * N + col] = (_Float16)(acc[mt][nt][r] * sc);
      }
    }
  } else if (MODE == 4) {
    if (n0 < INNER) {  // K half: row-major [M, INNER]
      _Float16* C = (_Float16*)Cout;
#pragma unroll
      for (int mt = 0; mt < 4; ++mt) {
        const size_t row = m0 + wm + mt * 16 + quad * 4;
#pragma unroll
        for (int nt = 0; nt < 4; ++nt) {
          const size_t col = n0 + wn + nt * 16 + l16;
#pragma unroll
          for (int r = 0; r < 4; ++r)
            C[(row + r) * INNER + col] = (_Float16)acc[mt][nt][r];
        }
      }
    } else {  // V half: scatter to vT[b][h][d][kv]
      _Float16* C = (_Float16*)Cout2;
      const int b = (int)(m0 >> 10);
#pragma unroll
      for (int mt = 0; mt < 4; ++mt) {
        const int kvb = (int)(m0 & 1023) + wm + mt * 16 + quad * 4;
#pragma unroll
        for (int nt = 0; nt < 4; ++nt) {
          const int col = (int)(n0 - INNER + wn + nt * 16 + l16);
          const int h = col >> 6, d = col & 63;
          half4v pk;
#pragma unroll
          for (int r = 0; r < 4; ++r) pk[r] = (_Float16)acc[mt][nt][r];
          *(half4v*)(C + (size_t)((b * NH + h) * DH + d) * SKV + kvb) = pk;
        }
      }
    }
  } else {
    float* C = (float*)Cout;
#pragma unroll
    for (int mt = 0; mt < 4; ++mt) {
      const size_t row = m0 + wm + mt * 16 + quad * 4;
#pragma unroll
      for (int nt = 0; nt < 4; ++nt) {
        const size_t col = n0 + wn + nt * 16 + l16;
        const float bb = bias[col];
#pragma unroll
        for (int r = 0; r < 4; ++r)
          C[(row + r) * N + col] = acc[mt][nt][r] + bb;
      }
    }
  }
}

// ---------------------------------------------------------------- fused projections
// Q-proj (512 blocks) + KV-proj (256 blocks) in one 768-block launch, reading
// fp32 x/ctx DIRECTLY. XCD-local mapping (r8-proven): xcd = b&7 owns a contiguous
// band of m-stripes; j%3 interleaves {Q,Q,KV} within the XCD -> A-stripes + weight
// panels served by ONE private L2. No LDS -> occupancy VGPR-bound; launch_bounds
// (256,3) caps ~170 VGPR so the grid's 3 blocks/CU stay resident.
__global__ __launch_bounds__(256, 3) void proj_fused(const float* __restrict__ x,
                                                     const float* __restrict__ ctx,
                                                     const _Float16* __restrict__ wqt,
                                                     const _Float16* __restrict__ wkvt,
                                                     _Float16* __restrict__ qh,
                                                     _Float16* __restrict__ kh,
                                                     _Float16* __restrict__ vth) {
  const int b = blockIdx.x;
  const int xcd = b & 7, j = b >> 3;
  const int seg = j % 3;
  if (seg == 2) {  // KV: M=4096, N=1024 (k|v), K=768; stripes 0..31, n 0..7
    const int jkv = j / 3;  // 0..31
    gemm_reg<4, 1, 2 * INNER, CD>((const void*)ctx, wkvt, kh, vth, nullptr,
                                  jkv & 7, xcd * 4 + (jkv >> 3));
  } else {  // Q: M=16384, N=512, K=1024 (scale folded); stripes 0..127, n 0..3
    const int jq = (j / 3) * 2 + seg;  // 0..63
    gemm_reg<3, 1, INNER, QD>((const void*)x, wqt, qh, nullptr, nullptr,
                              jq & 3, xcd * 16 + (jq >> 2));
  }
}

// ---------------------------------------------------------------- output projection
// 1024 blocks, XCD-local: xcd = b&7 owns aoh m-stripes [xcd*16, xcd*16+16).
__global__ __launch_bounds__(256, 3) void gemm_out(const _Float16* __restrict__ A,
                                                   const _Float16* __restrict__ Bt,
                                                   float* __restrict__ Cout,
                                                   const float* __restrict__ bias) {
  const int b = blockIdx.x;
  const int xcd = b & 7, i = b >> 3;  // i: 0..127
  gemm_reg<2, 0, QD, INNER>((const void*)A, Bt, Cout, nullptr, bias,
                            i & 7, xcd * 16 + (i >> 3));
}

// ---------------------------------------------------------------- flash attention v8
// (byte-identical to r8/r10/r11-green.) 32x32x16 MFMA. Swapped QK^T (S^T = K·Q^T):
// lane owns one q-row, softmax lane-local; P->PV-A transpose = 4 permlane32_swap;
// row-sums via ones-MFMA (same layout as o -> lane-local normalize). KV-tile 64,
// double-buffered LDS, one barrier per tile, prefetch-before-compute. XOR-swizzled
// tiles (blk ^= row&7) with pre-swizzled global source. Grid 1024, XCD swizzle.
// exp path: __builtin_exp2f ONLY (amdgcn builtin and raw asm both red in r7/r9).
// No setprio (A/B: +3us on this lockstep 4-wave kernel).
__global__ __launch_bounds__(256, 3) void flash_attn8(const _Float16* __restrict__ Q,
                                                      const _Float16* __restrict__ Kp,
                                                      const _Float16* __restrict__ Vt,
                                                      _Float16* __restrict__ O) {
  __shared__ _Float16 Ksb[2 * 64 * 64];  // [buf][kv64][d64], 16B-blk XOR by kv&7
  __shared__ _Float16 Vsb[2 * 64 * 64];  // [buf][d64][kv64], 16B-blk XOR by d&7
  const int tid = threadIdx.x;
  const int wave = tid >> 6, lane = tid & 63;
  const int l31 = lane & 31, hi = lane >> 5, x7 = lane & 7;

  // XCD-aware swizzle: 1024 blocks % 8 == 0 -> bijective chunked remap
  const int flat = blockIdx.x;
  const int nf = (flat & 7) * 128 + (flat >> 3);
  const int qblk = nf & 31, bh = nf >> 5;
  const int b = bh >> 3, h = bh & 7;

  const size_t qrow0 = (size_t)b * SQ + qblk * 128 + wave * 32;
  const _Float16* qptr = Q + qrow0 * INNER + h * DH;
  const _Float16* kbase = Kp + (size_t)b * SKV * INNER + h * DH;
  const _Float16* vbase = Vt + (size_t)bh * DH * SKV;

  // staging: linear LDS dest (tid*16B), pre-swizzled global src (blk ^= row&7)
  const int kr = tid >> 3;
  const int kb = (tid & 7) ^ (kr & 7);
  const _Float16* kg = kbase + (size_t)kr * INNER + kb * 8;
  const _Float16* vg = vbase + (size_t)kr * SKV + kb * 8;

#define STAGE_KV(bi, tt)                                                        \
  do {                                                                          \
    _Float16* _kl = Ksb + (bi) * 4096 + tid * 8;                                \
    _Float16* _vl = Vsb + (bi) * 4096 + tid * 8;                                \
    GLD16(kg + (size_t)((tt) * 64) * INNER, _kl);                               \
    GLD16(kg + (size_t)((tt) * 64 + 32) * INNER, _kl + 2048);                   \
    GLD16(vg + (tt) * 64, _vl);                                                 \
    GLD16(vg + (size_t)32 * SKV + (tt) * 64, _vl + 2048);                       \
  } while (0)

  half8 aq[4];
#pragma unroll
  for (int i = 0; i < 4; ++i)
    aq[i] = *(const half8*)(qptr + (size_t)l31 * INNER + i * 16 + hi * 8);

  int koff[4], voffB[4];
#pragma unroll
  for (int i = 0; i < 4; ++i)
    koff[i] = l31 * 64 + (((i * 2 + hi) ^ x7) << 3);
#pragma unroll
  for (int j = 0; j < 4; ++j)
    voffB[j] = l31 * 64 + (((j * 2 + hi) ^ x7) << 3);

  half8 ones;
#pragma unroll
  for (int j = 0; j < 8; ++j) ones[j] = (_Float16)1.0f;

  f32x16 o0 = {}, o1 = {}, osum = {};

  STAGE_KV(0, 0);

  for (int t = 0; t < SKV / 64; ++t) {
    __syncthreads();
    if (t < SKV / 64 - 1) STAGE_KV((t + 1) & 1, t + 1);
    const _Float16* ks = Ksb + (t & 1) * 4096;
    const _Float16* vs = Vsb + (t & 1) * 4096;

#pragma unroll
    for (int c2 = 0; c2 < 2; ++c2) {
      half8 ak[4];
#pragma unroll
      for (int i = 0; i < 4; ++i)
        ak[i] = *(const half8*)(ks + c2 * 2048 + koff[i]);

      f32x16 st = {};
#pragma unroll
      for (int i = 0; i < 4; ++i) st = MFMA32(ak[i], aq[i], st);

      unsigned w[8];
#pragma unroll
      for (int j = 0; j < 8; ++j) {
        float plo = __builtin_exp2f(st[2 * j]);
        float phi = __builtin_exp2f(st[2 * j + 1]);
        w[j] = __builtin_bit_cast(unsigned, __builtin_amdgcn_cvt_pkrtz(plo, phi));
      }
      PLSWAP(w[0], w[2]);
      PLSWAP(w[1], w[3]);
      PLSWAP(w[4], w[6]);
      PLSWAP(w[5], w[7]);
      uint4v u0 = {w[0], w[1], w[2], w[3]};
      uint4v u1 = {w[4], w[5], w[6], w[7]};
      half8 A0 = __builtin_bit_cast(half8, u0);
      half8 A1 = __builtin_bit_cast(half8, u1);

      osum = MFMA32(A0, ones, osum);
      osum = MFMA32(A1, ones, osum);

      {
        half8 bv00 = *(const half8*)(vs + 0 * 2048 + voffB[c2 * 2 + 0]);
        half8 bv10 = *(const half8*)(vs + 1 * 2048 + voffB[c2 * 2 + 0]);
        o0 = MFMA32(A0, bv00, o0);
        o1 = MFMA32(A0, bv10, o1);
        half8 bv01 = *(const half8*)(vs + 0 * 2048 + voffB[c2 * 2 + 1]);
        half8 bv11 = *(const half8*)(vs + 1 * 2048 + voffB[c2 * 2 + 1]);
        o0 = MFMA32(A1, bv01, o0);
        o1 = MFMA32(A1, bv11, o1);
      }
    }
  }

  float inv16[16];
#pragma unroll
  for (int r = 0; r < 16; ++r) inv16[r] = 1.0f / osum[r];

  _Float16* op = O + qrow0 * INNER + h * DH;
#pragma unroll
  for (int r = 0; r < 16; ++r) {
    const int q = (r & 3) + 8 * (r >> 2) + 4 * hi;
    op[(size_t)q * INNER + l31] = (_Float16)(o0[r] * inv16[r]);
    op[(size_t)q * INNER + 32 + l31] = (_Float16)(o1[r] * inv16[r]);
  }
#undef STAGE_KV
}

// ---------------------------------------------------------------- launcher
extern "C" void kernel_launch(void* const* d_in, const int* in_sizes, int n_in,
                              void* d_out, int out_size, void* d_ws, size_t ws_size,
                              hipStream_t stream) {
  const float* x   = (const float*)d_in[0];
  const float* ctx = (const float*)d_in[1];
  const float* Wq  = (const float*)d_in[2];
  const float* Wk  = (const float*)d_in[3];
  const float* Wv  = (const float*)d_in[4];
  const float* Wo  = (const float*)d_in[5];
  const float* bo  = (const float*)d_in[6];
  float* out = (float*)d_out;

  _Float16* ws = (_Float16*)d_ws;
  _Float16* wqt  = ws;                                   // [512,1024]
  _Float16* wkvt = wqt + (size_t)INNER * QD;             // [1024,768] (k rows, then v)
  _Float16* wot  = wkvt + (size_t)2 * INNER * CD;        // [1024,512]
  _Float16* qh   = wot + (size_t)QD * INNER;             // [16384,512]
  _Float16* kh   = qh + (size_t)BATCH * SQ * INNER;      // [4096,512]
  _Float16* vth  = kh + (size_t)BATCH * SKV * INNER;     // [4,8,64,1024]
  _Float16* aoh  = vth + (size_t)BATCH * SKV * INNER;    // [16384,512]

  // weight transposes only (proj reads fp32 x/ctx directly)
  transpose_all<<<dim3(32, 32, 4), 256, 0, stream>>>(Wq, Wk, Wv, Wo, wqt, wkvt, wot);

  // fused Q + KV projections (768 blocks, XCD-local A-stripes, fp32 A, no-LDS)
  proj_fused<<<dim3(768), 256, 0, stream>>>(x, ctx, wqt, wkvt, qh, kh, vth);

  // attention
  flash_attn8<<<dim3(BATCH * NH * SQ / 128), 256, 0, stream>>>(qh, kh, vth, aoh);

  // output projection + bias, fp32 out (1024 blocks, XCD-local, no-LDS)
  gemm_out<<<dim3(1024), 256, 0, stream>>>(aoh, wot, out, bo);
}

// Round 13
// 257.761 us; speedup vs baseline: 1.3942x; 1.3942x over previous
//
#include <hip/hip_runtime.h>

#define SQ 4096
#define SKV 1024
#define BATCH 4
#define NH 8
#define DH 64
#define QD 1024
#define CD 768
#define INNER 512

typedef _Float16 half8 __attribute__((ext_vector_type(8)));
typedef _Float16 half4v __attribute__((ext_vector_type(4)));
typedef float floatx4 __attribute__((ext_vector_type(4)));
typedef float f32x16 __attribute__((ext_vector_type(16)));
typedef unsigned int uint4v __attribute__((ext_vector_type(4)));

#define MFMA16(a, b, c) __builtin_amdgcn_mfma_f32_16x16x32_f16(a, b, c, 0, 0, 0)
#define MFMA32(a, b, c) __builtin_amdgcn_mfma_f32_32x32x16_f16(a, b, c, 0, 0, 0)

// v_permlane32_swap_b32: a' = {a.lo31, b.lo31}, b' = {a.hi31, b.hi31}
#define PLSWAP(a, b) asm("v_permlane32_swap_b32 %0, %1" : "+v"(a), "+v"(b))

// async global->LDS, 16B per lane; LDS dest = wave-uniform base + lane*16
#define GLD16(gptr, lptr)                                                            \
  __builtin_amdgcn_global_load_lds(                                                  \
      (const __attribute__((address_space(1))) unsigned int*)(const void*)(gptr),    \
      (__attribute__((address_space(3))) unsigned int*)(void*)(lptr), 16, 0, 0)

// ---------------------------------------------------------------- prep (cast + transposes)
// (r4/r6-green form.) Blocks [0, NCAST) cast x/ctx fp32->fp16 (2048 elems/block);
// blocks [NCAST, NCAST+4096) do the 4 weight transposes.
__global__ __launch_bounds__(256) void prep(const float* __restrict__ x,
                                            const float* __restrict__ ctx,
                                            const float* __restrict__ Wq,
                                            const float* __restrict__ Wk,
                                            const float* __restrict__ Wv,
                                            const float* __restrict__ Wo,
                                            _Float16* __restrict__ xh,
                                            _Float16* __restrict__ ctxh,
                                            _Float16* __restrict__ wqt,
                                            _Float16* __restrict__ wkvt,
                                            _Float16* __restrict__ wot) {
  __shared__ float tile[32][33];
  const size_t NX = (size_t)BATCH * SQ * QD;   // 16.7M (8192 blocks)
  const size_t NC = (size_t)BATCH * SKV * CD;  // 3.1M  (1536 blocks)
  const unsigned NCAST = (unsigned)((NX + NC) / 2048);

  if (blockIdx.x < NCAST) {  // -------- cast path
    size_t i = ((size_t)blockIdx.x * 256 + threadIdx.x) * 8;
    const float* s;
    _Float16* d;
    size_t off;
    if (i < NX) { s = x; d = xh; off = i; }
    else        { s = ctx; d = ctxh; off = i - NX; }
    floatx4 a = *(const floatx4*)(s + off);
    floatx4 b = *(const floatx4*)(s + off + 4);
    half8 h;
#pragma unroll
    for (int j = 0; j < 4; ++j) { h[j] = (_Float16)a[j]; h[4 + j] = (_Float16)b[j]; }
    *(half8*)(d + off) = h;
    return;
  }
  // -------- transpose path: src [R,C] fp32 -> dst [C,R] fp16
  const unsigned t = blockIdx.x - NCAST;
  const int z = t >> 10, rem = t & 1023;
  const float* src; _Float16* dst; int R, C;
  if (z == 0)      { src = Wq; dst = wqt;                        R = QD;    C = INNER; }
  else if (z == 1) { src = Wk; dst = wkvt;                       R = CD;    C = INNER; }
  else if (z == 2) { src = Wv; dst = wkvt + (size_t)INNER * CD;  R = CD;    C = INNER; }
  else             { src = Wo; dst = wot;                        R = INNER; C = QD;   }
  const int c0 = (rem & 31) * 32, r0 = (rem >> 5) * 32;
  if (c0 >= C || r0 >= R) return;
  const int tx = threadIdx.x & 31, ty = threadIdx.x >> 5;
#pragma unroll
  for (int i = 0; i < 32; i += 8)
    tile[ty + i][tx] = src[(size_t)(r0 + ty + i) * C + c0 + tx];
  __syncthreads();
#pragma unroll
  for (int i = 0; i < 32; i += 8)
    dst[(size_t)(c0 + ty + i) * R + r0 + tx] = (_Float16)tile[tx][ty + i];
}

// ---------------------------------------------------------------- 3-ring GEMM body
// C[M,N] = A[M,K] @ B[K,N], A row-major fp16, B transposed (Bt[N,K], fp16).
// Tile 128x128, BK=32, 4 waves (2x2 of 64x64). THREE-buffer LDS ring with COUNTED
// vmcnt: per step {s_waitcnt vmcnt(4) [tile t landed, t+1's 4 loads in flight] ->
// s_barrier -> issue STAGE(t+2) -> ds_read+MFMA}. Never vmcnt(0) in the main loop
// -> 2 compute phases of load-latency coverage (the dbuf __syncthreads loop drains
// the just-issued prefetch every step: r10/r11 PMC showed 5250 cyc/step, all pipes
// <26%). Ring-safety: vmcnt retires in order; buf (t+2)%3's readers (tile t-1)
// finished their ds_reads before passing barrier t (lgkmcnt precedes MFMA issue);
// side-effecting intrinsics (GLD16) are not reordered across s_barrier. r9's red
// bundled this ring with EXP2RAW (independently proven the failure cause in r7).
// T2 swizzle kept from r11-green: pre-swizzled global source blk ^= (row>>1)&3,
// frag-reads apply quad^r2 (LDS dest linear per global_load_lds rules).
// Block mapping XCD-LOCAL (launch sites): A-stripes fetched once per XCD L2.
// MODE 2: fp32 + bias. MODE 3: fp16 out scaled by 0.125*log2(e).
// MODE 4: merged k/v epilogue — n<512 -> kh row-major [M,512]; n>=512 -> vT scatter.
template <int MODE>
__device__ __forceinline__ void gemm_body(const _Float16* __restrict__ A,
                                          const _Float16* __restrict__ Bt,
                                          void* __restrict__ Cout,
                                          void* __restrict__ Cout2,
                                          const float* __restrict__ bias,
                                          int M, int N, int K, int bx, int by,
                                          _Float16* As16, _Float16* Bs) {
  const int tid = threadIdx.x;
  const int wave = tid >> 6, lane = tid & 63;
  const int quad = lane >> 4, l16 = lane & 15;
  const int wm = (wave >> 1) * 64, wn = (wave & 1) * 64;
  const size_t n0 = (size_t)bx * 128, m0 = (size_t)by * 128;

  floatx4 acc[4][4] = {};

  // pre-swizzled global sources (r11-green math)
  const int a16r = tid >> 2, a16b = (tid & 3) ^ ((a16r >> 1) & 3);
  const _Float16* ag = A + (m0 + a16r) * (size_t)K + a16b * 8;
  const _Float16* bg = Bt + (n0 + a16r) * (size_t)K + a16b * 8;

#define GSTAGE(bi, k0)                                                      \
  do {                                                                      \
    GLD16(ag + (k0), As16 + (bi)*4096 + tid * 8);                           \
    GLD16(ag + (k0) + (size_t)64 * K, As16 + (bi)*4096 + tid * 8 + 2048);   \
    GLD16(bg + (k0), Bs + (bi)*4096 + tid * 8);                             \
    GLD16(bg + (k0) + (size_t)64 * K, Bs + (bi)*4096 + tid * 8 + 2048);     \
  } while (0)

  const int NT = K / 32;  // >= 16 for all call sites
  GSTAGE(0, 0);
  GSTAGE(1, 32);
  int cb = 0;
  for (int t = 0; t < NT; ++t) {
    if (t + 1 < NT)
      asm volatile("s_waitcnt vmcnt(4)" ::: "memory");  // tile t landed; t+1 in flight
    else
      asm volatile("s_waitcnt vmcnt(0)" ::: "memory");  // final tile
    __builtin_amdgcn_sched_barrier(0);
    __builtin_amdgcn_s_barrier();  // all waves: tile t visible; buf (t+2)%3 free
    __builtin_amdgcn_sched_barrier(0);
    if (t + 2 < NT) {
      int nb = cb + 2; if (nb >= 3) nb -= 3;
      GSTAGE(nb, (t + 2) * 32);
    }
    const _Float16* as = As16 + cb * 4096;
    const _Float16* bs = Bs + cb * 4096;

    // swizzled frag reads: LDS blk b holds global blk b^key -> read blk quad^key
    const int r2 = (l16 >> 1) & 3;
    half8 af[4], bf[4];
#pragma unroll
    for (int mt = 0; mt < 4; ++mt)
      af[mt] = *(const half8*)(as + (wm + mt * 16 + l16) * 32 + (quad ^ r2) * 8);
#pragma unroll
    for (int nt = 0; nt < 4; ++nt)
      bf[nt] = *(const half8*)(bs + (wn + nt * 16 + l16) * 32 + (quad ^ r2) * 8);
    __builtin_amdgcn_s_setprio(1);
#pragma unroll
    for (int mt = 0; mt < 4; ++mt)
#pragma unroll
      for (int nt = 0; nt < 4; ++nt)
        acc[mt][nt] = MFMA16(af[mt], bf[nt], acc[mt][nt]);
    __builtin_amdgcn_s_setprio(0);
    cb = (cb == 2) ? 0 : cb + 1;
  }
#undef GSTAGE

  // epilogue: C/D layout row = quad*4+r, col = l16  (green forms)
  if (MODE == 3) {
    _Float16* C = (_Float16*)Cout;
    // fold softmax scale (1/8) and log2(e) into Q so attention uses exp2
    const float sc = 0.125f * 1.44269504088896f;
#pragma unroll
    for (int mt = 0; mt < 4; ++mt) {
      const size_t row = m0 + wm + mt * 16 + quad * 4;
#pragma unroll
      for (int nt = 0; nt < 4; ++nt) {
        const size_t col = n0 + wn + nt * 16 + l16;
#pragma unroll
        for (int r = 0; r < 4; ++r)
          C[(row + r) * N + col] = (_Float16)(acc[mt][nt][r] * sc);
      }
    }
  } else if (MODE == 4) {
    if (n0 < INNER) {  // K half: row-major [M, INNER]
      _Float16* C = (_Float16*)Cout;
#pragma unroll
      for (int mt = 0; mt < 4; ++mt) {
        const size_t row = m0 + wm + mt * 16 + quad * 4;
#pragma unroll
        for (int nt = 0; nt < 4; ++nt) {
          const size_t col = n0 + wn + nt * 16 + l16;
#pragma unroll
          for (int r = 0; r < 4; ++r)
            C[(row + r) * INNER + col] = (_Float16)acc[mt][nt][r];
        }
      }
    } else {  // V half: scatter to vT[b][h][d][kv]
      _Float16* C = (_Float16*)Cout2;
      const int b = (int)(m0 >> 10);
#pragma unroll
      for (int mt = 0; mt < 4; ++mt) {
        const int kvb = (int)(m0 & 1023) + wm + mt * 16 + quad * 4;
#pragma unroll
        for (int nt = 0; nt < 4; ++nt) {
          const int col = (int)(n0 - INNER + wn + nt * 16 + l16);
          const int h = col >> 6, d = col & 63;
          half4v pk;
#pragma unroll
          for (int r = 0; r < 4; ++r) pk[r] = (_Float16)acc[mt][nt][r];
          *(half4v*)(C + (size_t)((b * NH + h) * DH + d) * SKV + kvb) = pk;
        }
      }
    }
  } else {
    float* C = (float*)Cout;
#pragma unroll
    for (int mt = 0; mt < 4; ++mt) {
      const size_t row = m0 + wm + mt * 16 + quad * 4;
#pragma unroll
      for (int nt = 0; nt < 4; ++nt) {
        const size_t col = n0 + wn + nt * 16 + l16;
        const float bb = bias[col];
#pragma unroll
        for (int r = 0; r < 4; ++r)
          C[(row + r) * N + col] = acc[mt][nt][r] + bb;
      }
    }
  }
}

// ---------------------------------------------------------------- fused projections
// Q-proj (512 blocks) + KV-proj (256 blocks) in one 768-block launch, fp16 A.
// XCD-local mapping (r8-proven): xcd = b&7 owns a contiguous band of m-stripes;
// j%3 interleaves {Q,Q,KV} within the XCD -> A-stripes fetched once per XCD L2.
// LDS 48 KB (3-ring A 24K + B 24K) -> 3 blocks/CU; grid 768 = exactly 3/CU.
__global__ __launch_bounds__(256) void proj_fused(const _Float16* __restrict__ xh,
                                                  const _Float16* __restrict__ ctxh,
                                                  const _Float16* __restrict__ wqt,
                                                  const _Float16* __restrict__ wkvt,
                                                  _Float16* __restrict__ qh,
                                                  _Float16* __restrict__ kh,
                                                  _Float16* __restrict__ vth) {
  __shared__ _Float16 As16[3 * 128 * 32];
  __shared__ _Float16 Bs[3 * 128 * 32];
  const int b = blockIdx.x;
  const int xcd = b & 7, j = b >> 3;
  const int seg = j % 3;
  if (seg == 2) {  // KV: M=4096, N=1024 (k|v), K=768; stripes 0..31, n 0..7
    const int jkv = j / 3;  // 0..31
    gemm_body<4>(ctxh, wkvt, kh, vth, nullptr, BATCH * SKV, 2 * INNER, CD,
                 jkv & 7, xcd * 4 + (jkv >> 3), As16, Bs);
  } else {  // Q: M=16384, N=512, K=1024 (scale folded); stripes 0..127, n 0..3
    const int jq = (j / 3) * 2 + seg;  // 0..63
    gemm_body<3>(xh, wqt, qh, nullptr, nullptr, BATCH * SQ, INNER, QD,
                 jq & 3, xcd * 16 + (jq >> 2), As16, Bs);
  }
}

// ---------------------------------------------------------------- output projection
// 1024 blocks, XCD-local: xcd = b&7 owns aoh m-stripes [xcd*16, xcd*16+16).
__global__ __launch_bounds__(256) void gemm_out(const _Float16* __restrict__ A,
                                                const _Float16* __restrict__ Bt,
                                                float* __restrict__ Cout,
                                                const float* __restrict__ bias) {
  __shared__ _Float16 As16[3 * 128 * 32];
  __shared__ _Float16 Bs[3 * 128 * 32];
  const int b = blockIdx.x;
  const int xcd = b & 7, i = b >> 3;  // i: 0..127
  gemm_body<2>(A, Bt, Cout, nullptr, bias, BATCH * SQ, QD, INNER,
               i & 7, xcd * 16 + (i >> 3), As16, Bs);
}

// ---------------------------------------------------------------- flash attention v8
// (byte-identical to r8/r10/r11-green.) 32x32x16 MFMA. Swapped QK^T (S^T = K·Q^T):
// lane owns one q-row, softmax lane-local; P->PV-A transpose = 4 permlane32_swap;
// row-sums via ones-MFMA (same layout as o -> lane-local normalize). KV-tile 64,
// double-buffered LDS, one barrier per tile, prefetch-before-compute. XOR-swizzled
// tiles (blk ^= row&7) with pre-swizzled global source. Grid 1024, XCD swizzle.
// exp path: __builtin_exp2f ONLY (amdgcn builtin and raw asm both red in r7/r9).
// No setprio (A/B: +3us on this lockstep 4-wave kernel).
__global__ __launch_bounds__(256, 3) void flash_attn8(const _Float16* __restrict__ Q,
                                                      const _Float16* __restrict__ Kp,
                                                      const _Float16* __restrict__ Vt,
                                                      _Float16* __restrict__ O) {
  __shared__ _Float16 Ksb[2 * 64 * 64];  // [buf][kv64][d64], 16B-blk XOR by kv&7
  __shared__ _Float16 Vsb[2 * 64 * 64];  // [buf][d64][kv64], 16B-blk XOR by d&7
  const int tid = threadIdx.x;
  const int wave = tid >> 6, lane = tid & 63;
  const int l31 = lane & 31, hi = lane >> 5, x7 = lane & 7;

  // XCD-aware swizzle: 1024 blocks % 8 == 0 -> bijective chunked remap
  const int flat = blockIdx.x;
  const int nf = (flat & 7) * 128 + (flat >> 3);
  const int qblk = nf & 31, bh = nf >> 5;
  const int b = bh >> 3, h = bh & 7;

  const size_t qrow0 = (size_t)b * SQ + qblk * 128 + wave * 32;
  const _Float16* qptr = Q + qrow0 * INNER + h * DH;
  const _Float16* kbase = Kp + (size_t)b * SKV * INNER + h * DH;
  const _Float16* vbase = Vt + (size_t)bh * DH * SKV;

  // staging: linear LDS dest (tid*16B), pre-swizzled global src (blk ^= row&7)
  const int kr = tid >> 3;
  const int kb = (tid & 7) ^ (kr & 7);
  const _Float16* kg = kbase + (size_t)kr * INNER + kb * 8;
  const _Float16* vg = vbase + (size_t)kr * SKV + kb * 8;

#define STAGE_KV(bi, tt)                                                        \
  do {                                                                          \
    _Float16* _kl = Ksb + (bi) * 4096 + tid * 8;                                \
    _Float16* _vl = Vsb + (bi) * 4096 + tid * 8;                                \
    GLD16(kg + (size_t)((tt) * 64) * INNER, _kl);                               \
    GLD16(kg + (size_t)((tt) * 64 + 32) * INNER, _kl + 2048);                   \
    GLD16(vg + (tt) * 64, _vl);                                                 \
    GLD16(vg + (size_t)32 * SKV + (tt) * 64, _vl + 2048);                       \
  } while (0)

  half8 aq[4];
#pragma unroll
  for (int i = 0; i < 4; ++i)
    aq[i] = *(const half8*)(qptr + (size_t)l31 * INNER + i * 16 + hi * 8);

  int koff[4], voffB[4];
#pragma unroll
  for (int i = 0; i < 4; ++i)
    koff[i] = l31 * 64 + (((i * 2 + hi) ^ x7) << 3);
#pragma unroll
  for (int j = 0; j < 4; ++j)
    voffB[j] = l31 * 64 + (((j * 2 + hi) ^ x7) << 3);

  half8 ones;
#pragma unroll
  for (int j = 0; j < 8; ++j) ones[j] = (_Float16)1.0f;

  f32x16 o0 = {}, o1 = {}, osum = {};

  STAGE_KV(0, 0);

  for (int t = 0; t < SKV / 64; ++t) {
    __syncthreads();
    if (t < SKV / 64 - 1) STAGE_KV((t + 1) & 1, t + 1);
    const _Float16* ks = Ksb + (t & 1) * 4096;
    const _Float16* vs = Vsb + (t & 1) * 4096;

#pragma unroll
    for (int c2 = 0; c2 < 2; ++c2) {
      half8 ak[4];
#pragma unroll
      for (int i = 0; i < 4; ++i)
        ak[i] = *(const half8*)(ks + c2 * 2048 + koff[i]);

      f32x16 st = {};
#pragma unroll
      for (int i = 0; i < 4; ++i) st = MFMA32(ak[i], aq[i], st);

      unsigned w[8];
#pragma unroll
      for (int j = 0; j < 8; ++j) {
        float plo = __builtin_exp2f(st[2 * j]);
        float phi = __builtin_exp2f(st[2 * j + 1]);
        w[j] = __builtin_bit_cast(unsigned, __builtin_amdgcn_cvt_pkrtz(plo, phi));
      }
      PLSWAP(w[0], w[2]);
      PLSWAP(w[1], w[3]);
      PLSWAP(w[4], w[6]);
      PLSWAP(w[5], w[7]);
      uint4v u0 = {w[0], w[1], w[2], w[3]};
      uint4v u1 = {w[4], w[5], w[6], w[7]};
      half8 A0 = __builtin_bit_cast(half8, u0);
      half8 A1 = __builtin_bit_cast(half8, u1);

      osum = MFMA32(A0, ones, osum);
      osum = MFMA32(A1, ones, osum);

      {
        half8 bv00 = *(const half8*)(vs + 0 * 2048 + voffB[c2 * 2 + 0]);
        half8 bv10 = *(const half8*)(vs + 1 * 2048 + voffB[c2 * 2 + 0]);
        o0 = MFMA32(A0, bv00, o0);
        o1 = MFMA32(A0, bv10, o1);
        half8 bv01 = *(const half8*)(vs + 0 * 2048 + voffB[c2 * 2 + 1]);
        half8 bv11 = *(const half8*)(vs + 1 * 2048 + voffB[c2 * 2 + 1]);
        o0 = MFMA32(A1, bv01, o0);
        o1 = MFMA32(A1, bv11, o1);
      }
    }
  }

  float inv16[16];
#pragma unroll
  for (int r = 0; r < 16; ++r) inv16[r] = 1.0f / osum[r];

  _Float16* op = O + qrow0 * INNER + h * DH;
#pragma unroll
  for (int r = 0; r < 16; ++r) {
    const int q = (r & 3) + 8 * (r >> 2) + 4 * hi;
    op[(size_t)q * INNER + l31] = (_Float16)(o0[r] * inv16[r]);
    op[(size_t)q * INNER + 32 + l31] = (_Float16)(o1[r] * inv16[r]);
  }
#undef STAGE_KV
}

// ---------------------------------------------------------------- launcher
extern "C" void kernel_launch(void* const* d_in, const int* in_sizes, int n_in,
                              void* d_out, int out_size, void* d_ws, size_t ws_size,
                              hipStream_t stream) {
  const float* x   = (const float*)d_in[0];
  const float* ctx = (const float*)d_in[1];
  const float* Wq  = (const float*)d_in[2];
  const float* Wk  = (const float*)d_in[3];
  const float* Wv  = (const float*)d_in[4];
  const float* Wo  = (const float*)d_in[5];
  const float* bo  = (const float*)d_in[6];
  float* out = (float*)d_out;

  const size_t NX = (size_t)BATCH * SQ * QD;   // 16.7M
  const size_t NC = (size_t)BATCH * SKV * CD;  // 3.1M

  _Float16* ws = (_Float16*)d_ws;
  _Float16* xh   = ws;                                   // [16384,1024] fp16
  _Float16* ctxh = xh + NX;                              // [4096,768]
  _Float16* wqt  = ctxh + NC;                            // [512,1024]
  _Float16* wkvt = wqt + (size_t)INNER * QD;             // [1024,768] (k rows, then v)
  _Float16* wot  = wkvt + (size_t)2 * INNER * CD;        // [1024,512]
  _Float16* qh   = wot + (size_t)QD * INNER;             // [16384,512]
  _Float16* kh   = qh + (size_t)BATCH * SQ * INNER;      // [4096,512]
  _Float16* vth  = kh + (size_t)BATCH * SKV * INNER;     // [4,8,64,1024]
  _Float16* aoh  = xh;  // alias: xh dead after proj_fused; aoh (8.4M) fits in NX

  // cast (9728 blocks) + weight transposes (4096 blocks) in one launch
  prep<<<dim3((unsigned)((NX + NC) / 2048) + 4096), 256, 0, stream>>>(
      x, ctx, Wq, Wk, Wv, Wo, xh, ctxh, wqt, wkvt, wot);

  // fused Q + KV projections (768 blocks, XCD-local A-stripes, fp16 A, 3-ring)
  proj_fused<<<dim3(768), 256, 0, stream>>>(xh, ctxh, wqt, wkvt, qh, kh, vth);

  // attention
  flash_attn8<<<dim3(BATCH * NH * SQ / 128), 256, 0, stream>>>(qh, kh, vth, aoh);

  // output projection + bias, fp32 out (1024 blocks, XCD-local, 3-ring)
  gemm_out<<<dim3(1024), 256, 0, stream>>>(aoh, wot, out, bo);
}

// Round 14
// 255.951 us; speedup vs baseline: 1.4041x; 1.0071x over previous
//
#include <hip/hip_runtime.h>

#define SQ 4096
#define SKV 1024
#define BATCH 4
#define NH 8
#define DH 64
#define QD 1024
#define CD 768
#define INNER 512

typedef _Float16 half8 __attribute__((ext_vector_type(8)));
typedef _Float16 half4v __attribute__((ext_vector_type(4)));
typedef float floatx4 __attribute__((ext_vector_type(4)));
typedef float f32x16 __attribute__((ext_vector_type(16)));
typedef unsigned int uint4v __attribute__((ext_vector_type(4)));

#define MFMA16(a, b, c) __builtin_amdgcn_mfma_f32_16x16x32_f16(a, b, c, 0, 0, 0)
#define MFMA32(a, b, c) __builtin_amdgcn_mfma_f32_32x32x16_f16(a, b, c, 0, 0, 0)

// v_permlane32_swap_b32: a' = {a.lo31, b.lo31}, b' = {a.hi31, b.hi31}
#define PLSWAP(a, b) asm("v_permlane32_swap_b32 %0, %1" : "+v"(a), "+v"(b))

// async global->LDS, 16B per lane; LDS dest = wave-uniform base + lane*16
#define GLD16(gptr, lptr)                                                            \
  __builtin_amdgcn_global_load_lds(                                                  \
      (const __attribute__((address_space(1))) unsigned int*)(const void*)(gptr),    \
      (__attribute__((address_space(3))) unsigned int*)(void*)(lptr), 16, 0, 0)

// ---------------------------------------------------------------- prep (cast + transposes)
// (r4/r6/r13-green form.) Blocks [0, NCAST) cast x/ctx fp32->fp16 (2048 elems/blk);
// blocks [NCAST, NCAST+4096) do the 4 weight transposes.
__global__ __launch_bounds__(256) void prep(const float* __restrict__ x,
                                            const float* __restrict__ ctx,
                                            const float* __restrict__ Wq,
                                            const float* __restrict__ Wk,
                                            const float* __restrict__ Wv,
                                            const float* __restrict__ Wo,
                                            _Float16* __restrict__ xh,
                                            _Float16* __restrict__ ctxh,
                                            _Float16* __restrict__ wqt,
                                            _Float16* __restrict__ wkvt,
                                            _Float16* __restrict__ wot) {
  __shared__ float tile[32][33];
  const size_t NX = (size_t)BATCH * SQ * QD;   // 16.7M (8192 blocks)
  const size_t NC = (size_t)BATCH * SKV * CD;  // 3.1M  (1536 blocks)
  const unsigned NCAST = (unsigned)((NX + NC) / 2048);

  if (blockIdx.x < NCAST) {  // -------- cast path
    size_t i = ((size_t)blockIdx.x * 256 + threadIdx.x) * 8;
    const float* s;
    _Float16* d;
    size_t off;
    if (i < NX) { s = x; d = xh; off = i; }
    else        { s = ctx; d = ctxh; off = i - NX; }
    floatx4 a = *(const floatx4*)(s + off);
    floatx4 b = *(const floatx4*)(s + off + 4);
    half8 h;
#pragma unroll
    for (int j = 0; j < 4; ++j) { h[j] = (_Float16)a[j]; h[4 + j] = (_Float16)b[j]; }
    *(half8*)(d + off) = h;
    return;
  }
  // -------- transpose path: src [R,C] fp32 -> dst [C,R] fp16
  const unsigned t = blockIdx.x - NCAST;
  const int z = t >> 10, rem = t & 1023;
  const float* src; _Float16* dst; int R, C;
  if (z == 0)      { src = Wq; dst = wqt;                        R = QD;    C = INNER; }
  else if (z == 1) { src = Wk; dst = wkvt;                       R = CD;    C = INNER; }
  else if (z == 2) { src = Wv; dst = wkvt + (size_t)INNER * CD;  R = CD;    C = INNER; }
  else             { src = Wo; dst = wot;                        R = INNER; C = QD;   }
  const int c0 = (rem & 31) * 32, r0 = (rem >> 5) * 32;
  if (c0 >= C || r0 >= R) return;
  const int tx = threadIdx.x & 31, ty = threadIdx.x >> 5;
#pragma unroll
  for (int i = 0; i < 32; i += 8)
    tile[ty + i][tx] = src[(size_t)(r0 + ty + i) * C + c0 + tx];
  __syncthreads();
#pragma unroll
  for (int i = 0; i < 32; i += 8)
    dst[(size_t)(c0 + ty + i) * R + r0 + tx] = (_Float16)tile[tx][ty + i];
}

// ---------------------------------------------------------------- GEMM body
// C[M,N] = A[M,K] @ B[K,N], A row-major fp16, B transposed (Bt[N,K], fp16).
// Tile 128x128, BK=32, 4 waves (2x2 of 64x64).
// NBUF=3: counted-vmcnt ring (r13-green): {vmcnt(4) -> s_barrier -> stage(t+2) ->
//   compute}; never vmcnt(0) in-loop; 48 KB LDS -> 3 blocks/CU.
// NBUF=2: r8-green dbuf: {__syncthreads -> stage(t+1) -> compute}; 32 KB LDS ->
//   4 blocks/CU at __launch_bounds__(256,4) (tail removal for 1024-block grids).
// T2 swizzle (r11/r13-green): pre-swizzled global source blk ^= (row>>1)&3,
// frag-reads apply quad^r2 (LDS dest linear per global_load_lds rules).
// Block mapping XCD-LOCAL (launch sites): A-stripes fetched once per XCD L2.
// MODE 2: fp32 + bias. MODE 3: fp16 out scaled by 0.125*log2(e).
// MODE 4: merged k/v epilogue — n<512 -> kh row-major [M,512]; n>=512 -> vT scatter.
template <int MODE, int NBUF>
__device__ __forceinline__ void gemm_body(const _Float16* __restrict__ A,
                                          const _Float16* __restrict__ Bt,
                                          void* __restrict__ Cout,
                                          void* __restrict__ Cout2,
                                          const float* __restrict__ bias,
                                          int M, int N, int K, int bx, int by,
                                          _Float16* As16, _Float16* Bs) {
  const int tid = threadIdx.x;
  const int wave = tid >> 6, lane = tid & 63;
  const int quad = lane >> 4, l16 = lane & 15;
  const int wm = (wave >> 1) * 64, wn = (wave & 1) * 64;
  const size_t n0 = (size_t)bx * 128, m0 = (size_t)by * 128;

  floatx4 acc[4][4] = {};

  // pre-swizzled global sources (r11-green math)
  const int a16r = tid >> 2, a16b = (tid & 3) ^ ((a16r >> 1) & 3);
  const _Float16* ag = A + (m0 + a16r) * (size_t)K + a16b * 8;
  const _Float16* bg = Bt + (n0 + a16r) * (size_t)K + a16b * 8;

#define GSTAGE(bi, k0)                                                      \
  do {                                                                      \
    GLD16(ag + (k0), As16 + (bi)*4096 + tid * 8);                           \
    GLD16(ag + (k0) + (size_t)64 * K, As16 + (bi)*4096 + tid * 8 + 2048);   \
    GLD16(bg + (k0), Bs + (bi)*4096 + tid * 8);                             \
    GLD16(bg + (k0) + (size_t)64 * K, Bs + (bi)*4096 + tid * 8 + 2048);     \
  } while (0)

  const int NT = K / 32;
  GSTAGE(0, 0);
  if (NBUF == 3) GSTAGE(1, 32);
  int cb = 0;
  for (int t = 0; t < NT; ++t) {
    if (NBUF == 3) {
      if (t + 1 < NT)
        asm volatile("s_waitcnt vmcnt(4)" ::: "memory");  // tile t landed; t+1 flying
      else
        asm volatile("s_waitcnt vmcnt(0)" ::: "memory");  // final tile
      __builtin_amdgcn_sched_barrier(0);
      __builtin_amdgcn_s_barrier();  // tile t visible; buf (t+2)%3 free
      __builtin_amdgcn_sched_barrier(0);
      if (t + 2 < NT) {
        int nb = cb + 2; if (nb >= 3) nb -= 3;
        GSTAGE(nb, (t + 2) * 32);
      }
    } else {
      __syncthreads();  // drains tile t; prev readers of buf (t+1)&1 done
      if (t + 1 < NT) GSTAGE((t + 1) & 1, (t + 1) * 32);
    }
    const _Float16* as = As16 + cb * 4096;
    const _Float16* bs = Bs + cb * 4096;

    // swizzled frag reads: LDS blk b holds global blk b^key -> read blk quad^key
    const int r2 = (l16 >> 1) & 3;
    half8 af[4], bf[4];
#pragma unroll
    for (int mt = 0; mt < 4; ++mt)
      af[mt] = *(const half8*)(as + (wm + mt * 16 + l16) * 32 + (quad ^ r2) * 8);
#pragma unroll
    for (int nt = 0; nt < 4; ++nt)
      bf[nt] = *(const half8*)(bs + (wn + nt * 16 + l16) * 32 + (quad ^ r2) * 8);
    __builtin_amdgcn_s_setprio(1);
#pragma unroll
    for (int mt = 0; mt < 4; ++mt)
#pragma unroll
      for (int nt = 0; nt < 4; ++nt)
        acc[mt][nt] = MFMA16(af[mt], bf[nt], acc[mt][nt]);
    __builtin_amdgcn_s_setprio(0);
    cb = (NBUF == 3) ? ((cb == 2) ? 0 : cb + 1) : ((t + 1) & 1);
  }
#undef GSTAGE

  // epilogue: C/D layout row = quad*4+r, col = l16  (green forms)
  if (MODE == 3) {
    _Float16* C = (_Float16*)Cout;
    // fold softmax scale (1/8) and log2(e) into Q so attention uses exp2
    const float sc = 0.125f * 1.44269504088896f;
#pragma unroll
    for (int mt = 0; mt < 4; ++mt) {
      const size_t row = m0 + wm + mt * 16 + quad * 4;
#pragma unroll
      for (int nt = 0; nt < 4; ++nt) {
        const size_t col = n0 + wn + nt * 16 + l16;
#pragma unroll
        for (int r = 0; r < 4; ++r)
          C[(row + r) * N + col] = (_Float16)(acc[mt][nt][r] * sc);
      }
    }
  } else if (MODE == 4) {
    if (n0 < INNER) {  // K half: row-major [M, INNER]
      _Float16* C = (_Float16*)Cout;
#pragma unroll
      for (int mt = 0; mt < 4; ++mt) {
        const size_t row = m0 + wm + mt * 16 + quad * 4;
#pragma unroll
        for (int nt = 0; nt < 4; ++nt) {
          const size_t col = n0 + wn + nt * 16 + l16;
#pragma unroll
          for (int r = 0; r < 4; ++r)
            C[(row + r) * INNER + col] = (_Float16)acc[mt][nt][r];
        }
      }
    } else {  // V half: scatter to vT[b][h][d][kv]
      _Float16* C = (_Float16*)Cout2;
      const int b = (int)(m0 >> 10);
#pragma unroll
      for (int mt = 0; mt < 4; ++mt) {
        const int kvb = (int)(m0 & 1023) + wm + mt * 16 + quad * 4;
#pragma unroll
        for (int nt = 0; nt < 4; ++nt) {
          const int col = (int)(n0 - INNER + wn + nt * 16 + l16);
          const int h = col >> 6, d = col & 63;
          half4v pk;
#pragma unroll
          for (int r = 0; r < 4; ++r) pk[r] = (_Float16)acc[mt][nt][r];
          *(half4v*)(C + (size_t)((b * NH + h) * DH + d) * SKV + kvb) = pk;
        }
      }
    }
  } else {
    float* C = (float*)Cout;
#pragma unroll
    for (int mt = 0; mt < 4; ++mt) {
      const size_t row = m0 + wm + mt * 16 + quad * 4;
#pragma unroll
      for (int nt = 0; nt < 4; ++nt) {
        const size_t col = n0 + wn + nt * 16 + l16;
        const float bb = bias[col];
#pragma unroll
        for (int r = 0; r < 4; ++r)
          C[(row + r) * N + col] = acc[mt][nt][r] + bb;
      }
    }
  }
}

// ---------------------------------------------------------------- fused projections
// Q-proj (512 blocks) + KV-proj (256 blocks) in one 768-block launch, fp16 A.
// XCD-local mapping (r8-proven). LDS 48 KB (3-ring) -> 3 blocks/CU; 768 grid =
// exactly 3/CU resident: zero tail.
__global__ __launch_bounds__(256) void proj_fused(const _Float16* __restrict__ xh,
                                                  const _Float16* __restrict__ ctxh,
                                                  const _Float16* __restrict__ wqt,
                                                  const _Float16* __restrict__ wkvt,
                                                  _Float16* __restrict__ qh,
                                                  _Float16* __restrict__ kh,
                                                  _Float16* __restrict__ vth) {
  __shared__ _Float16 As16[3 * 128 * 32];
  __shared__ _Float16 Bs[3 * 128 * 32];
  const int b = blockIdx.x;
  const int xcd = b & 7, j = b >> 3;
  const int seg = j % 3;
  if (seg == 2) {  // KV: M=4096, N=1024 (k|v), K=768; stripes 0..31, n 0..7
    const int jkv = j / 3;  // 0..31
    gemm_body<4, 3>(ctxh, wkvt, kh, vth, nullptr, BATCH * SKV, 2 * INNER, CD,
                    jkv & 7, xcd * 4 + (jkv >> 3), As16, Bs);
  } else {  // Q: M=16384, N=512, K=1024 (scale folded); stripes 0..127, n 0..3
    const int jq = (j / 3) * 2 + seg;  // 0..63
    gemm_body<3, 3>(xh, wqt, qh, nullptr, nullptr, BATCH * SQ, INNER, QD,
                    jq & 3, xcd * 16 + (jq >> 2), As16, Bs);
  }
}

// ---------------------------------------------------------------- output projection
// 1024 blocks. TAIL FIX (this round): r13's 48 KB ring capped this at 3 blocks/CU
// -> 768 resident + 256-block tail (33% of dispatch at 1/3 occupancy). Switch to
// r8-green dbuf (32 KB) + launch_bounds(256,4): 4 blocks/CU -> all 1024 resident.
// VGPR: 80 used, cap at 4 waves/SIMD = 128 -> no spill.
__global__ __launch_bounds__(256, 4) void gemm_out(const _Float16* __restrict__ A,
                                                   const _Float16* __restrict__ Bt,
                                                   float* __restrict__ Cout,
                                                   const float* __restrict__ bias) {
  __shared__ _Float16 As16[2 * 128 * 32];
  __shared__ _Float16 Bs[2 * 128 * 32];
  const int b = blockIdx.x;
  const int xcd = b & 7, i = b >> 3;  // i: 0..127
  gemm_body<2, 2>(A, Bt, Cout, nullptr, bias, BATCH * SQ, QD, INNER,
                  i & 7, xcd * 16 + (i >> 3), As16, Bs);
}

// ---------------------------------------------------------------- flash attention v8
// Math byte-identical to r8/r13-green. TAIL FIX (this round): launch_bounds
// (256,3) -> (256,4). VGPR_Count is 60 <= 64 so 4 blocks/CU fits (LDS 4x32=128KB
// <= 160); 1024 blocks = exactly 4/CU x 256 CU -> zero tail (was 768+256 = 33%
// of dispatch at 1/3 occupancy).
// exp path: __builtin_exp2f ONLY (amdgcn builtin and raw asm both red r7/r9).
// No setprio (A/B: +3us on this lockstep 4-wave kernel).
__global__ __launch_bounds__(256, 4) void flash_attn8(const _Float16* __restrict__ Q,
                                                      const _Float16* __restrict__ Kp,
                                                      const _Float16* __restrict__ Vt,
                                                      _Float16* __restrict__ O) {
  __shared__ _Float16 Ksb[2 * 64 * 64];  // [buf][kv64][d64], 16B-blk XOR by kv&7
  __shared__ _Float16 Vsb[2 * 64 * 64];  // [buf][d64][kv64], 16B-blk XOR by d&7
  const int tid = threadIdx.x;
  const int wave = tid >> 6, lane = tid & 63;
  const int l31 = lane & 31, hi = lane >> 5, x7 = lane & 7;

  // XCD-aware swizzle: 1024 blocks % 8 == 0 -> bijective chunked remap
  const int flat = blockIdx.x;
  const int nf = (flat & 7) * 128 + (flat >> 3);
  const int qblk = nf & 31, bh = nf >> 5;
  const int b = bh >> 3, h = bh & 7;

  const size_t qrow0 = (size_t)b * SQ + qblk * 128 + wave * 32;
  const _Float16* qptr = Q + qrow0 * INNER + h * DH;
  const _Float16* kbase = Kp + (size_t)b * SKV * INNER + h * DH;
  const _Float16* vbase = Vt + (size_t)bh * DH * SKV;

  // staging: linear LDS dest (tid*16B), pre-swizzled global src (blk ^= row&7)
  const int kr = tid >> 3;
  const int kb = (tid & 7) ^ (kr & 7);
  const _Float16* kg = kbase + (size_t)kr * INNER + kb * 8;
  const _Float16* vg = vbase + (size_t)kr * SKV + kb * 8;

#define STAGE_KV(bi, tt)                                                        \
  do {                                                                          \
    _Float16* _kl = Ksb + (bi) * 4096 + tid * 8;                                \
    _Float16* _vl = Vsb + (bi) * 4096 + tid * 8;                                \
    GLD16(kg + (size_t)((tt) * 64) * INNER, _kl);                               \
    GLD16(kg + (size_t)((tt) * 64 + 32) * INNER, _kl + 2048);                   \
    GLD16(vg + (tt) * 64, _vl);                                                 \
    GLD16(vg + (size_t)32 * SKV + (tt) * 64, _vl + 2048);                       \
  } while (0)

  half8 aq[4];
#pragma unroll
  for (int i = 0; i < 4; ++i)
    aq[i] = *(const half8*)(qptr + (size_t)l31 * INNER + i * 16 + hi * 8);

  int koff[4], voffB[4];
#pragma unroll
  for (int i = 0; i < 4; ++i)
    koff[i] = l31 * 64 + (((i * 2 + hi) ^ x7) << 3);
#pragma unroll
  for (int j = 0; j < 4; ++j)
    voffB[j] = l31 * 64 + (((j * 2 + hi) ^ x7) << 3);

  half8 ones;
#pragma unroll
  for (int j = 0; j < 8; ++j) ones[j] = (_Float16)1.0f;

  f32x16 o0 = {}, o1 = {}, osum = {};

  STAGE_KV(0, 0);

  for (int t = 0; t < SKV / 64; ++t) {
    __syncthreads();
    if (t < SKV / 64 - 1) STAGE_KV((t + 1) & 1, t + 1);
    const _Float16* ks = Ksb + (t & 1) * 4096;
    const _Float16* vs = Vsb + (t & 1) * 4096;

#pragma unroll
    for (int c2 = 0; c2 < 2; ++c2) {
      half8 ak[4];
#pragma unroll
      for (int i = 0; i < 4; ++i)
        ak[i] = *(const half8*)(ks + c2 * 2048 + koff[i]);

      f32x16 st = {};
#pragma unroll
      for (int i = 0; i < 4; ++i) st = MFMA32(ak[i], aq[i], st);

      unsigned w[8];
#pragma unroll
      for (int j = 0; j < 8; ++j) {
        float plo = __builtin_exp2f(st[2 * j]);
        float phi = __builtin_exp2f(st[2 * j + 1]);
        w[j] = __builtin_bit_cast(unsigned, __builtin_amdgcn_cvt_pkrtz(plo, phi));
      }
      PLSWAP(w[0], w[2]);
      PLSWAP(w[1], w[3]);
      PLSWAP(w[4], w[6]);
      PLSWAP(w[5], w[7]);
      uint4v u0 = {w[0], w[1], w[2], w[3]};
      uint4v u1 = {w[4], w[5], w[6], w[7]};
      half8 A0 = __builtin_bit_cast(half8, u0);
      half8 A1 = __builtin_bit_cast(half8, u1);

      osum = MFMA32(A0, ones, osum);
      osum = MFMA32(A1, ones, osum);

      {
        half8 bv00 = *(const half8*)(vs + 0 * 2048 + voffB[c2 * 2 + 0]);
        half8 bv10 = *(const half8*)(vs + 1 * 2048 + voffB[c2 * 2 + 0]);
        o0 = MFMA32(A0, bv00, o0);
        o1 = MFMA32(A0, bv10, o1);
        half8 bv01 = *(const half8*)(vs + 0 * 2048 + voffB[c2 * 2 + 1]);
        half8 bv11 = *(const half8*)(vs + 1 * 2048 + voffB[c2 * 2 + 1]);
        o0 = MFMA32(A1, bv01, o0);
        o1 = MFMA32(A1, bv11, o1);
      }
    }
  }

  float inv16[16];
#pragma unroll
  for (int r = 0; r < 16; ++r) inv16[r] = 1.0f / osum[r];

  _Float16* op = O + qrow0 * INNER + h * DH;
#pragma unroll
  for (int r = 0; r < 16; ++r) {
    const int q = (r & 3) + 8 * (r >> 2) + 4 * hi;
    op[(size_t)q * INNER + l31] = (_Float16)(o0[r] * inv16[r]);
    op[(size_t)q * INNER + 32 + l31] = (_Float16)(o1[r] * inv16[r]);
  }
#undef STAGE_KV
}

// ---------------------------------------------------------------- launcher
extern "C" void kernel_launch(void* const* d_in, const int* in_sizes, int n_in,
                              void* d_out, int out_size, void* d_ws, size_t ws_size,
                              hipStream_t stream) {
  const float* x   = (const float*)d_in[0];
  const float* ctx = (const float*)d_in[1];
  const float* Wq  = (const float*)d_in[2];
  const float* Wk  = (const float*)d_in[3];
  const float* Wv  = (const float*)d_in[4];
  const float* Wo  = (const float*)d_in[5];
  const float* bo  = (const float*)d_in[6];
  float* out = (float*)d_out;

  const size_t NX = (size_t)BATCH * SQ * QD;   // 16.7M
  const size_t NC = (size_t)BATCH * SKV * CD;  // 3.1M

  _Float16* ws = (_Float16*)d_ws;
  _Float16* xh   = ws;                                   // [16384,1024] fp16
  _Float16* ctxh = xh + NX;                              // [4096,768]
  _Float16* wqt  = ctxh + NC;                            // [512,1024]
  _Float16* wkvt = wqt + (size_t)INNER * QD;             // [1024,768] (k rows, then v)
  _Float16* wot  = wkvt + (size_t)2 * INNER * CD;        // [1024,512]
  _Float16* qh   = wot + (size_t)QD * INNER;             // [16384,512]
  _Float16* kh   = qh + (size_t)BATCH * SQ * INNER;      // [4096,512]
  _Float16* vth  = kh + (size_t)BATCH * SKV * INNER;     // [4,8,64,1024]
  _Float16* aoh  = xh;  // alias: xh dead after proj_fused; aoh (8.4M) fits in NX

  // cast (9728 blocks) + weight transposes (4096 blocks) in one launch
  prep<<<dim3((unsigned)((NX + NC) / 2048) + 4096), 256, 0, stream>>>(
      x, ctx, Wq, Wk, Wv, Wo, xh, ctxh, wqt, wkvt, wot);

  // fused Q + KV projections (768 blocks = exact 3/CU, XCD-local, fp16 A, 3-ring)
  proj_fused<<<dim3(768), 256, 0, stream>>>(xh, ctxh, wqt, wkvt, qh, kh, vth);

  // attention (1024 blocks = exact 4/CU, zero tail)
  flash_attn8<<<dim3(BATCH * NH * SQ / 128), 256, 0, stream>>>(qh, kh, vth, aoh);

  // output projection + bias, fp32 out (1024 blocks = exact 4/CU, dbuf 32KB)
  gemm_out<<<dim3(1024), 256, 0, stream>>>(aoh, wot, out, bo);
}

// Round 15
// 255.421 us; speedup vs baseline: 1.4070x; 1.0021x over previous
//
#include <hip/hip_runtime.h>

#define SQ 4096
#define SKV 1024
#define BATCH 4
#define NH 8
#define DH 64
#define QD 1024
#define CD 768
#define INNER 512

typedef _Float16 half8 __attribute__((ext_vector_type(8)));
typedef _Float16 half4v __attribute__((ext_vector_type(4)));
typedef float floatx4 __attribute__((ext_vector_type(4)));
typedef float f32x16 __attribute__((ext_vector_type(16)));
typedef unsigned int uint4v __attribute__((ext_vector_type(4)));

#define MFMA16(a, b, c) __builtin_amdgcn_mfma_f32_16x16x32_f16(a, b, c, 0, 0, 0)
#define MFMA32(a, b, c) __builtin_amdgcn_mfma_f32_32x32x16_f16(a, b, c, 0, 0, 0)

// v_permlane32_swap_b32: a' = {a.lo31, b.lo31}, b' = {a.hi31, b.hi31}
#define PLSWAP(a, b) asm("v_permlane32_swap_b32 %0, %1" : "+v"(a), "+v"(b))

// async global->LDS, 16B per lane; LDS dest = wave-uniform base + lane*16
#define GLD16(gptr, lptr)                                                            \
  __builtin_amdgcn_global_load_lds(                                                  \
      (const __attribute__((address_space(1))) unsigned int*)(const void*)(gptr),    \
      (__attribute__((address_space(3))) unsigned int*)(void*)(lptr), 16, 0, 0)

// ---------------------------------------------------------------- prep (cast + transposes)
// (r4/r6/r13/r14-green form.) Blocks [0, NCAST) cast x/ctx fp32->fp16; blocks
// [NCAST, NCAST+4096) do the 4 weight transposes.
__global__ __launch_bounds__(256) void prep(const float* __restrict__ x,
                                            const float* __restrict__ ctx,
                                            const float* __restrict__ Wq,
                                            const float* __restrict__ Wk,
                                            const float* __restrict__ Wv,
                                            const float* __restrict__ Wo,
                                            _Float16* __restrict__ xh,
                                            _Float16* __restrict__ ctxh,
                                            _Float16* __restrict__ wqt,
                                            _Float16* __restrict__ wkvt,
                                            _Float16* __restrict__ wot) {
  __shared__ float tile[32][33];
  const size_t NX = (size_t)BATCH * SQ * QD;   // 16.7M (8192 blocks)
  const size_t NC = (size_t)BATCH * SKV * CD;  // 3.1M  (1536 blocks)
  const unsigned NCAST = (unsigned)((NX + NC) / 2048);

  if (blockIdx.x < NCAST) {  // -------- cast path
    size_t i = ((size_t)blockIdx.x * 256 + threadIdx.x) * 8;
    const float* s;
    _Float16* d;
    size_t off;
    if (i < NX) { s = x; d = xh; off = i; }
    else        { s = ctx; d = ctxh; off = i - NX; }
    floatx4 a = *(const floatx4*)(s + off);
    floatx4 b = *(const floatx4*)(s + off + 4);
    half8 h;
#pragma unroll
    for (int j = 0; j < 4; ++j) { h[j] = (_Float16)a[j]; h[4 + j] = (_Float16)b[j]; }
    *(half8*)(d + off) = h;
    return;
  }
  // -------- transpose path: src [R,C] fp32 -> dst [C,R] fp16
  const unsigned t = blockIdx.x - NCAST;
  const int z = t >> 10, rem = t & 1023;
  const float* src; _Float16* dst; int R, C;
  if (z == 0)      { src = Wq; dst = wqt;                        R = QD;    C = INNER; }
  else if (z == 1) { src = Wk; dst = wkvt;                       R = CD;    C = INNER; }
  else if (z == 2) { src = Wv; dst = wkvt + (size_t)INNER * CD;  R = CD;    C = INNER; }
  else             { src = Wo; dst = wot;                        R = INNER; C = QD;   }
  const int c0 = (rem & 31) * 32, r0 = (rem >> 5) * 32;
  if (c0 >= C || r0 >= R) return;
  const int tx = threadIdx.x & 31, ty = threadIdx.x >> 5;
#pragma unroll
  for (int i = 0; i < 32; i += 8)
    tile[ty + i][tx] = src[(size_t)(r0 + ty + i) * C + c0 + tx];
  __syncthreads();
#pragma unroll
  for (int i = 0; i < 32; i += 8)
    dst[(size_t)(c0 + ty + i) * R + r0 + tx] = (_Float16)tile[tx][ty + i];
}

// ---------------------------------------------------------------- GEMM body
// C[M,N] = A[M,K] @ B[K,N], A row-major fp16, B transposed (Bt[N,K], fp16).
// Tile 128x128, BK=32, 4 waves (2x2 of 64x64).
// THIS ROUND: K/N are TEMPLATE parameters (all call sites compile-time: 1024/768/
// 512). Mechanism: runtime K forced per-step v_mul/v_add address chains on 6 load
// streams; constant K strength-reduces to folded immediates, and unroll-2 halves
// loop control. (m97 @K=4096 runs the same structure at ~0.3us/step vs our ~1.9
// at K<=1024 — per-step overhead is un-amortized at small K.)
// NBUF=3: counted-vmcnt ring (r13-green): {vmcnt(4) -> s_barrier -> stage(t+2) ->
//   compute}; never vmcnt(0) in-loop; 48 KB LDS -> 3 blocks/CU.
// NBUF=2: r8-green dbuf: {__syncthreads -> stage(t+1) -> compute}; 32 KB LDS.
// T2 swizzle (r11/r13-green): pre-swizzled global source blk ^= (row>>1)&3,
// frag-reads apply quad^r2 (LDS dest linear per global_load_lds rules).
// Block mapping XCD-LOCAL (launch sites): A-stripes fetched once per XCD L2.
// MODE 2: fp32 + bias. MODE 3: fp16 out scaled by 0.125*log2(e).
// MODE 4: merged k/v epilogue — n<512 -> kh row-major [M,512]; n>=512 -> vT scatter.
template <int MODE, int NBUF, int K, int N>
__device__ __forceinline__ void gemm_body(const _Float16* __restrict__ A,
                                          const _Float16* __restrict__ Bt,
                                          void* __restrict__ Cout,
                                          void* __restrict__ Cout2,
                                          const float* __restrict__ bias,
                                          int bx, int by,
                                          _Float16* As16, _Float16* Bs) {
  const int tid = threadIdx.x;
  const int wave = tid >> 6, lane = tid & 63;
  const int quad = lane >> 4, l16 = lane & 15;
  const int wm = (wave >> 1) * 64, wn = (wave & 1) * 64;
  const size_t n0 = (size_t)bx * 128, m0 = (size_t)by * 128;

  floatx4 acc[4][4] = {};

  // pre-swizzled global sources (r11-green math)
  const int a16r = tid >> 2, a16b = (tid & 3) ^ ((a16r >> 1) & 3);
  const _Float16* ag = A + (m0 + a16r) * (size_t)K + a16b * 8;
  const _Float16* bg = Bt + (n0 + a16r) * (size_t)K + a16b * 8;

#define GSTAGE(bi, k0)                                                      \
  do {                                                                      \
    GLD16(ag + (k0), As16 + (bi)*4096 + tid * 8);                           \
    GLD16(ag + (k0) + (size_t)64 * K, As16 + (bi)*4096 + tid * 8 + 2048);   \
    GLD16(bg + (k0), Bs + (bi)*4096 + tid * 8);                             \
    GLD16(bg + (k0) + (size_t)64 * K, Bs + (bi)*4096 + tid * 8 + 2048);     \
  } while (0)

  constexpr int NT = K / 32;
  GSTAGE(0, 0);
  if (NBUF == 3) GSTAGE(1, 32);
  int cb = 0;
#pragma unroll 2
  for (int t = 0; t < NT; ++t) {
    if (NBUF == 3) {
      if (t + 1 < NT)
        asm volatile("s_waitcnt vmcnt(4)" ::: "memory");  // tile t landed; t+1 flying
      else
        asm volatile("s_waitcnt vmcnt(0)" ::: "memory");  // final tile
      __builtin_amdgcn_sched_barrier(0);
      __builtin_amdgcn_s_barrier();  // tile t visible; buf (t+2)%3 free
      __builtin_amdgcn_sched_barrier(0);
      if (t + 2 < NT) {
        int nb = cb + 2; if (nb >= 3) nb -= 3;
        GSTAGE(nb, (t + 2) * 32);
      }
    } else {
      __syncthreads();  // drains tile t; prev readers of buf (t+1)&1 done
      if (t + 1 < NT) GSTAGE((t + 1) & 1, (t + 1) * 32);
    }
    const _Float16* as = As16 + cb * 4096;
    const _Float16* bs = Bs + cb * 4096;

    // swizzled frag reads: LDS blk b holds global blk b^key -> read blk quad^key
    const int r2 = (l16 >> 1) & 3;
    half8 af[4], bf[4];
#pragma unroll
    for (int mt = 0; mt < 4; ++mt)
      af[mt] = *(const half8*)(as + (wm + mt * 16 + l16) * 32 + (quad ^ r2) * 8);
#pragma unroll
    for (int nt = 0; nt < 4; ++nt)
      bf[nt] = *(const half8*)(bs + (wn + nt * 16 + l16) * 32 + (quad ^ r2) * 8);
    __builtin_amdgcn_s_setprio(1);
#pragma unroll
    for (int mt = 0; mt < 4; ++mt)
#pragma unroll
      for (int nt = 0; nt < 4; ++nt)
        acc[mt][nt] = MFMA16(af[mt], bf[nt], acc[mt][nt]);
    __builtin_amdgcn_s_setprio(0);
    cb = (NBUF == 3) ? ((cb == 2) ? 0 : cb + 1) : ((t + 1) & 1);
  }
#undef GSTAGE

  // epilogue: C/D layout row = quad*4+r, col = l16  (green forms)
  if (MODE == 3) {
    _Float16* C = (_Float16*)Cout;
    // fold softmax scale (1/8) and log2(e) into Q so attention uses exp2
    const float sc = 0.125f * 1.44269504088896f;
#pragma unroll
    for (int mt = 0; mt < 4; ++mt) {
      const size_t row = m0 + wm + mt * 16 + quad * 4;
#pragma unroll
      for (int nt = 0; nt < 4; ++nt) {
        const size_t col = n0 + wn + nt * 16 + l16;
#pragma unroll
        for (int r = 0; r < 4; ++r)
          C[(row + r) * N + col] = (_Float16)(acc[mt][nt][r] * sc);
      }
    }
  } else if (MODE == 4) {
    if (n0 < INNER) {  // K half: row-major [M, INNER]
      _Float16* C = (_Float16*)Cout;
#pragma unroll
      for (int mt = 0; mt < 4; ++mt) {
        const size_t row = m0 + wm + mt * 16 + quad * 4;
#pragma unroll
      for (int nt = 0; nt < 4; ++nt) {
          const size_t col = n0 + wn + nt * 16 + l16;
#pragma unroll
          for (int r = 0; r < 4; ++r)
            C[(row + r) * INNER + col] = (_Float16)acc[mt][nt][r];
        }
      }
    } else {  // V half: scatter to vT[b][h][d][kv]
      _Float16* C = (_Float16*)Cout2;
      const int b = (int)(m0 >> 10);
#pragma unroll
      for (int mt = 0; mt < 4; ++mt) {
        const int kvb = (int)(m0 & 1023) + wm + mt * 16 + quad * 4;
#pragma unroll
        for (int nt = 0; nt < 4; ++nt) {
          const int col = (int)(n0 - INNER + wn + nt * 16 + l16);
          const int h = col >> 6, d = col & 63;
          half4v pk;
#pragma unroll
          for (int r = 0; r < 4; ++r) pk[r] = (_Float16)acc[mt][nt][r];
          *(half4v*)(C + (size_t)((b * NH + h) * DH + d) * SKV + kvb) = pk;
        }
      }
    }
  } else {
    float* C = (float*)Cout;
#pragma unroll
    for (int mt = 0; mt < 4; ++mt) {
      const size_t row = m0 + wm + mt * 16 + quad * 4;
#pragma unroll
      for (int nt = 0; nt < 4; ++nt) {
        const size_t col = n0 + wn + nt * 16 + l16;
        const float bb = bias[col];
#pragma unroll
        for (int r = 0; r < 4; ++r)
          C[(row + r) * N + col] = acc[mt][nt][r] + bb;
      }
    }
  }
}

// ---------------------------------------------------------------- fused projections
// Q-proj (512 blocks) + KV-proj (256 blocks) in one 768-block launch, fp16 A.
// XCD-local mapping (r8-proven). LDS 48 KB (3-ring) -> 3 blocks/CU; 768 grid =
// exactly 3/CU resident: zero tail. K compile-time: 1024 (Q) / 768 (KV).
__global__ __launch_bounds__(256) void proj_fused(const _Float16* __restrict__ xh,
                                                  const _Float16* __restrict__ ctxh,
                                                  const _Float16* __restrict__ wqt,
                                                  const _Float16* __restrict__ wkvt,
                                                  _Float16* __restrict__ qh,
                                                  _Float16* __restrict__ kh,
                                                  _Float16* __restrict__ vth) {
  __shared__ _Float16 As16[3 * 128 * 32];
  __shared__ _Float16 Bs[3 * 128 * 32];
  const int b = blockIdx.x;
  const int xcd = b & 7, j = b >> 3;
  const int seg = j % 3;
  if (seg == 2) {  // KV: M=4096, N=1024 (k|v), K=768; stripes 0..31, n 0..7
    const int jkv = j / 3;  // 0..31
    gemm_body<4, 3, CD, 2 * INNER>(ctxh, wkvt, kh, vth, nullptr,
                                   jkv & 7, xcd * 4 + (jkv >> 3), As16, Bs);
  } else {  // Q: M=16384, N=512, K=1024 (scale folded); stripes 0..127, n 0..3
    const int jq = (j / 3) * 2 + seg;  // 0..63
    gemm_body<3, 3, QD, INNER>(xh, wqt, qh, nullptr, nullptr,
                               jq & 3, xcd * 16 + (jq >> 2), As16, Bs);
  }
}

// ---------------------------------------------------------------- output projection
// 1024 blocks = exact 4/CU (dbuf 32KB + launch_bounds(256,4): zero tail, r14-green).
// K compile-time: 512.
__global__ __launch_bounds__(256, 4) void gemm_out(const _Float16* __restrict__ A,
                                                   const _Float16* __restrict__ Bt,
                                                   float* __restrict__ Cout,
                                                   const float* __restrict__ bias) {
  __shared__ _Float16 As16[2 * 128 * 32];
  __shared__ _Float16 Bs[2 * 128 * 32];
  const int b = blockIdx.x;
  const int xcd = b & 7, i = b >> 3;  // i: 0..127
  gemm_body<2, 2, INNER, QD>(A, Bt, Cout, nullptr, bias,
                             i & 7, xcd * 16 + (i >> 3), As16, Bs);
}

// ---------------------------------------------------------------- flash attention v8
// (byte-identical to r14-green.) 32x32x16 MFMA. Swapped QK^T (S^T = K·Q^T): lane
// owns one q-row, softmax lane-local; P->PV-A transpose = 4 permlane32_swap;
// row-sums via ones-MFMA (same layout as o -> lane-local normalize). KV-tile 64,
// double-buffered LDS, one barrier per tile, prefetch-before-compute. XOR-swizzled
// tiles (blk ^= row&7) with pre-swizzled global source. Grid 1024, XCD swizzle.
// exp path: __builtin_exp2f ONLY (amdgcn builtin and raw asm both red r7/r9 —
// mechanism unresolved, change banned). No setprio (A/B: +3us, lockstep waves).
__global__ __launch_bounds__(256, 4) void flash_attn8(const _Float16* __restrict__ Q,
                                                      const _Float16* __restrict__ Kp,
                                                      const _Float16* __restrict__ Vt,
                                                      _Float16* __restrict__ O) {
  __shared__ _Float16 Ksb[2 * 64 * 64];  // [buf][kv64][d64], 16B-blk XOR by kv&7
  __shared__ _Float16 Vsb[2 * 64 * 64];  // [buf][d64][kv64], 16B-blk XOR by d&7
  const int tid = threadIdx.x;
  const int wave = tid >> 6, lane = tid & 63;
  const int l31 = lane & 31, hi = lane >> 5, x7 = lane & 7;

  // XCD-aware swizzle: 1024 blocks % 8 == 0 -> bijective chunked remap
  const int flat = blockIdx.x;
  const int nf = (flat & 7) * 128 + (flat >> 3);
  const int qblk = nf & 31, bh = nf >> 5;
  const int b = bh >> 3, h = bh & 7;

  const size_t qrow0 = (size_t)b * SQ + qblk * 128 + wave * 32;
  const _Float16* qptr = Q + qrow0 * INNER + h * DH;
  const _Float16* kbase = Kp + (size_t)b * SKV * INNER + h * DH;
  const _Float16* vbase = Vt + (size_t)bh * DH * SKV;

  // staging: linear LDS dest (tid*16B), pre-swizzled global src (blk ^= row&7)
  const int kr = tid >> 3;
  const int kb = (tid & 7) ^ (kr & 7);
  const _Float16* kg = kbase + (size_t)kr * INNER + kb * 8;
  const _Float16* vg = vbase + (size_t)kr * SKV + kb * 8;

#define STAGE_KV(bi, tt)                                                        \
  do {                                                                          \
    _Float16* _kl = Ksb + (bi) * 4096 + tid * 8;                                \
    _Float16* _vl = Vsb + (bi) * 4096 + tid * 8;                                \
    GLD16(kg + (size_t)((tt) * 64) * INNER, _kl);                               \
    GLD16(kg + (size_t)((tt) * 64 + 32) * INNER, _kl + 2048);                   \
    GLD16(vg + (tt) * 64, _vl);                                                 \
    GLD16(vg + (size_t)32 * SKV + (tt) * 64, _vl + 2048);                       \
  } while (0)

  half8 aq[4];
#pragma unroll
  for (int i = 0; i < 4; ++i)
    aq[i] = *(const half8*)(qptr + (size_t)l31 * INNER + i * 16 + hi * 8);

  int koff[4], voffB[4];
#pragma unroll
  for (int i = 0; i < 4; ++i)
    koff[i] = l31 * 64 + (((i * 2 + hi) ^ x7) << 3);
#pragma unroll
  for (int j = 0; j < 4; ++j)
    voffB[j] = l31 * 64 + (((j * 2 + hi) ^ x7) << 3);

  half8 ones;
#pragma unroll
  for (int j = 0; j < 8; ++j) ones[j] = (_Float16)1.0f;

  f32x16 o0 = {}, o1 = {}, osum = {};

  STAGE_KV(0, 0);

  for (int t = 0; t < SKV / 64; ++t) {
    __syncthreads();
    if (t < SKV / 64 - 1) STAGE_KV((t + 1) & 1, t + 1);
    const _Float16* ks = Ksb + (t & 1) * 4096;
    const _Float16* vs = Vsb + (t & 1) * 4096;

#pragma unroll
    for (int c2 = 0; c2 < 2; ++c2) {
      half8 ak[4];
#pragma unroll
      for (int i = 0; i < 4; ++i)
        ak[i] = *(const half8*)(ks + c2 * 2048 + koff[i]);

      f32x16 st = {};
#pragma unroll
      for (int i = 0; i < 4; ++i) st = MFMA32(ak[i], aq[i], st);

      unsigned w[8];
#pragma unroll
      for (int j = 0; j < 8; ++j) {
        float plo = __builtin_exp2f(st[2 * j]);
        float phi = __builtin_exp2f(st[2 * j + 1]);
        w[j] = __builtin_bit_cast(unsigned, __builtin_amdgcn_cvt_pkrtz(plo, phi));
      }
      PLSWAP(w[0], w[2]);
      PLSWAP(w[1], w[3]);
      PLSWAP(w[4], w[6]);
      PLSWAP(w[5], w[7]);
      uint4v u0 = {w[0], w[1], w[2], w[3]};
      uint4v u1 = {w[4], w[5], w[6], w[7]};
      half8 A0 = __builtin_bit_cast(half8, u0);
      half8 A1 = __builtin_bit_cast(half8, u1);

      osum = MFMA32(A0, ones, osum);
      osum = MFMA32(A1, ones, osum);

      {
        half8 bv00 = *(const half8*)(vs + 0 * 2048 + voffB[c2 * 2 + 0]);
        half8 bv10 = *(const half8*)(vs + 1 * 2048 + voffB[c2 * 2 + 0]);
        o0 = MFMA32(A0, bv00, o0);
        o1 = MFMA32(A0, bv10, o1);
        half8 bv01 = *(const half8*)(vs + 0 * 2048 + voffB[c2 * 2 + 1]);
        half8 bv11 = *(const half8*)(vs + 1 * 2048 + voffB[c2 * 2 + 1]);
        o0 = MFMA32(A1, bv01, o0);
        o1 = MFMA32(A1, bv11, o1);
      }
    }
  }

  float inv16[16];
#pragma unroll
  for (int r = 0; r < 16; ++r) inv16[r] = 1.0f / osum[r];

  _Float16* op = O + qrow0 * INNER + h * DH;
#pragma unroll
  for (int r = 0; r < 16; ++r) {
    const int q = (r & 3) + 8 * (r >> 2) + 4 * hi;
    op[(size_t)q * INNER + l31] = (_Float16)(o0[r] * inv16[r]);
    op[(size_t)q * INNER + 32 + l31] = (_Float16)(o1[r] * inv16[r]);
  }
#undef STAGE_KV
}

// ---------------------------------------------------------------- launcher
extern "C" void kernel_launch(void* const* d_in, const int* in_sizes, int n_in,
                              void* d_out, int out_size, void* d_ws, size_t ws_size,
                              hipStream_t stream) {
  const float* x   = (const float*)d_in[0];
  const float* ctx = (const float*)d_in[1];
  const float* Wq  = (const float*)d_in[2];
  const float* Wk  = (const float*)d_in[3];
  const float* Wv  = (const float*)d_in[4];
  const float* Wo  = (const float*)d_in[5];
  const float* bo  = (const float*)d_in[6];
  float* out = (float*)d_out;

  const size_t NX = (size_t)BATCH * SQ * QD;   // 16.7M
  const size_t NC = (size_t)BATCH * SKV * CD;  // 3.1M

  _Float16* ws = (_Float16*)d_ws;
  _Float16* xh   = ws;                                   // [16384,1024] fp16
  _Float16* ctxh = xh + NX;                              // [4096,768]
  _Float16* wqt  = ctxh + NC;                            // [512,1024]
  _Float16* wkvt = wqt + (size_t)INNER * QD;             // [1024,768] (k rows, then v)
  _Float16* wot  = wkvt + (size_t)2 * INNER * CD;        // [1024,512]
  _Float16* qh   = wot + (size_t)QD * INNER;             // [16384,512]
  _Float16* kh   = qh + (size_t)BATCH * SQ * INNER;      // [4096,512]
  _Float16* vth  = kh + (size_t)BATCH * SKV * INNER;     // [4,8,64,1024]
  _Float16* aoh  = xh;  // alias: xh dead after proj_fused; aoh (8.4M) fits in NX

  // cast (9728 blocks) + weight transposes (4096 blocks) in one launch
  prep<<<dim3((unsigned)((NX + NC) / 2048) + 4096), 256, 0, stream>>>(
      x, ctx, Wq, Wk, Wv, Wo, xh, ctxh, wqt, wkvt, wot);

  // fused Q + KV projections (768 blocks = exact 3/CU, XCD-local, fp16 A, 3-ring)
  proj_fused<<<dim3(768), 256, 0, stream>>>(xh, ctxh, wqt, wkvt, qh, kh, vth);

  // attention (1024 blocks, zero tail)
  flash_attn8<<<dim3(BATCH * NH * SQ / 128), 256, 0, stream>>>(qh, kh, vth, aoh);

  // output projection + bias, fp32 out (1024 blocks = exact 4/CU, dbuf 32KB)
  gemm_out<<<dim3(1024), 256, 0, stream>>>(aoh, wot, out, bo);
}

// Round 16
// 250.268 us; speedup vs baseline: 1.4359x; 1.0206x over previous
//
#include <hip/hip_runtime.h>

#define SQ 4096
#define SKV 1024
#define BATCH 4
#define NH 8
#define DH 64
#define QD 1024
#define CD 768
#define INNER 512

typedef _Float16 half8 __attribute__((ext_vector_type(8)));
typedef _Float16 half4v __attribute__((ext_vector_type(4)));
typedef float floatx4 __attribute__((ext_vector_type(4)));
typedef float f32x16 __attribute__((ext_vector_type(16)));
typedef unsigned int uint4v __attribute__((ext_vector_type(4)));

#define MFMA16(a, b, c) __builtin_amdgcn_mfma_f32_16x16x32_f16(a, b, c, 0, 0, 0)
#define MFMA32(a, b, c) __builtin_amdgcn_mfma_f32_32x32x16_f16(a, b, c, 0, 0, 0)

// v_permlane32_swap_b32: a' = {a.lo31, b.lo31}, b' = {a.hi31, b.hi31}
#define PLSWAP(a, b) asm("v_permlane32_swap_b32 %0, %1" : "+v"(a), "+v"(b))

// async global->LDS, 16B per lane; LDS dest = wave-uniform base + lane*16
#define GLD16(gptr, lptr)                                                            \
  __builtin_amdgcn_global_load_lds(                                                  \
      (const __attribute__((address_space(1))) unsigned int*)(const void*)(gptr),    \
      (__attribute__((address_space(3))) unsigned int*)(void*)(lptr), 16, 0, 0)

// ---------------------------------------------------------------- prep (cast + transposes)
// (r13/r14/r15-green form.) Blocks [0, NCAST) cast x/ctx fp32->fp16; blocks
// [NCAST, NCAST+4096) do the 4 weight transposes.
__global__ __launch_bounds__(256) void prep(const float* __restrict__ x,
                                            const float* __restrict__ ctx,
                                            const float* __restrict__ Wq,
                                            const float* __restrict__ Wk,
                                            const float* __restrict__ Wv,
                                            const float* __restrict__ Wo,
                                            _Float16* __restrict__ xh,
                                            _Float16* __restrict__ ctxh,
                                            _Float16* __restrict__ wqt,
                                            _Float16* __restrict__ wkvt,
                                            _Float16* __restrict__ wot) {
  __shared__ float tile[32][33];
  const size_t NX = (size_t)BATCH * SQ * QD;   // 16.7M (8192 blocks)
  const size_t NC = (size_t)BATCH * SKV * CD;  // 3.1M  (1536 blocks)
  const unsigned NCAST = (unsigned)((NX + NC) / 2048);

  if (blockIdx.x < NCAST) {  // -------- cast path
    size_t i = ((size_t)blockIdx.x * 256 + threadIdx.x) * 8;
    const float* s;
    _Float16* d;
    size_t off;
    if (i < NX) { s = x; d = xh; off = i; }
    else        { s = ctx; d = ctxh; off = i - NX; }
    floatx4 a = *(const floatx4*)(s + off);
    floatx4 b = *(const floatx4*)(s + off + 4);
    half8 h;
#pragma unroll
    for (int j = 0; j < 4; ++j) { h[j] = (_Float16)a[j]; h[4 + j] = (_Float16)b[j]; }
    *(half8*)(d + off) = h;
    return;
  }
  // -------- transpose path: src [R,C] fp32 -> dst [C,R] fp16
  const unsigned t = blockIdx.x - NCAST;
  const int z = t >> 10, rem = t & 1023;
  const float* src; _Float16* dst; int R, C;
  if (z == 0)      { src = Wq; dst = wqt;                        R = QD;    C = INNER; }
  else if (z == 1) { src = Wk; dst = wkvt;                       R = CD;    C = INNER; }
  else if (z == 2) { src = Wv; dst = wkvt + (size_t)INNER * CD;  R = CD;    C = INNER; }
  else             { src = Wo; dst = wot;                        R = INNER; C = QD;   }
  const int c0 = (rem & 31) * 32, r0 = (rem >> 5) * 32;
  if (c0 >= C || r0 >= R) return;
  const int tx = threadIdx.x & 31, ty = threadIdx.x >> 5;
#pragma unroll
  for (int i = 0; i < 32; i += 8)
    tile[ty + i][tx] = src[(size_t)(r0 + ty + i) * C + c0 + tx];
  __syncthreads();
#pragma unroll
  for (int i = 0; i < 32; i += 8)
    dst[(size_t)(c0 + ty + i) * R + r0 + tx] = (_Float16)tile[tx][ty + i];
}

// ---------------------------------------------------------------- 128x128 GEMM body
// (r15-green, unchanged.) C[M,N] = A[M,K] @ Bt[N,K]^T, fp16. Tile 128x128, BK=32,
// 4 waves. Ring-3 counted vmcnt: {vmcnt(4) -> s_barrier -> stage(t+2) -> compute};
// never vmcnt(0) in-loop. T2 swizzle: src blk ^= (row>>1)&3, reads apply quad^r2.
// XCD-local block mapping at launch sites.
// MODE 3: fp16 out scaled by 0.125*log2(e). MODE 4: merged k/v epilogue.
template <int MODE, int K, int N>
__device__ __forceinline__ void gemm_body(const _Float16* __restrict__ A,
                                          const _Float16* __restrict__ Bt,
                                          void* __restrict__ Cout,
                                          void* __restrict__ Cout2,
                                          int bx, int by,
                                          _Float16* As16, _Float16* Bs) {
  const int tid = threadIdx.x;
  const int wave = tid >> 6, lane = tid & 63;
  const int quad = lane >> 4, l16 = lane & 15;
  const int wm = (wave >> 1) * 64, wn = (wave & 1) * 64;
  const size_t n0 = (size_t)bx * 128, m0 = (size_t)by * 128;

  floatx4 acc[4][4] = {};

  const int a16r = tid >> 2, a16b = (tid & 3) ^ ((a16r >> 1) & 3);
  const _Float16* ag = A + (m0 + a16r) * (size_t)K + a16b * 8;
  const _Float16* bg = Bt + (n0 + a16r) * (size_t)K + a16b * 8;

#define GSTAGE(bi, k0)                                                      \
  do {                                                                      \
    GLD16(ag + (k0), As16 + (bi)*4096 + tid * 8);                           \
    GLD16(ag + (k0) + (size_t)64 * K, As16 + (bi)*4096 + tid * 8 + 2048);   \
    GLD16(bg + (k0), Bs + (bi)*4096 + tid * 8);                             \
    GLD16(bg + (k0) + (size_t)64 * K, Bs + (bi)*4096 + tid * 8 + 2048);     \
  } while (0)

  constexpr int NT = K / 32;
  GSTAGE(0, 0);
  GSTAGE(1, 32);
  int cb = 0;
#pragma unroll 2
  for (int t = 0; t < NT; ++t) {
    if (t + 1 < NT)
      asm volatile("s_waitcnt vmcnt(4)" ::: "memory");  // tile t landed; t+1 flying
    else
      asm volatile("s_waitcnt vmcnt(0)" ::: "memory");  // final tile
    __builtin_amdgcn_sched_barrier(0);
    __builtin_amdgcn_s_barrier();  // tile t visible; buf (t+2)%3 free
    __builtin_amdgcn_sched_barrier(0);
    if (t + 2 < NT) {
      int nb = cb + 2; if (nb >= 3) nb -= 3;
      GSTAGE(nb, (t + 2) * 32);
    }
    const _Float16* as = As16 + cb * 4096;
    const _Float16* bs = Bs + cb * 4096;

    const int r2 = (l16 >> 1) & 3;
    half8 af[4], bf[4];
#pragma unroll
    for (int mt = 0; mt < 4; ++mt)
      af[mt] = *(const half8*)(as + (wm + mt * 16 + l16) * 32 + (quad ^ r2) * 8);
#pragma unroll
    for (int nt = 0; nt < 4; ++nt)
      bf[nt] = *(const half8*)(bs + (wn + nt * 16 + l16) * 32 + (quad ^ r2) * 8);
    __builtin_amdgcn_s_setprio(1);
#pragma unroll
    for (int mt = 0; mt < 4; ++mt)
#pragma unroll
      for (int nt = 0; nt < 4; ++nt)
        acc[mt][nt] = MFMA16(af[mt], bf[nt], acc[mt][nt]);
    __builtin_amdgcn_s_setprio(0);
    cb = (cb == 2) ? 0 : cb + 1;
  }
#undef GSTAGE

  // epilogue: C/D layout row = quad*4+r, col = l16  (green forms)
  if (MODE == 3) {
    _Float16* C = (_Float16*)Cout;
    const float sc = 0.125f * 1.44269504088896f;
#pragma unroll
    for (int mt = 0; mt < 4; ++mt) {
      const size_t row = m0 + wm + mt * 16 + quad * 4;
#pragma unroll
      for (int nt = 0; nt < 4; ++nt) {
        const size_t col = n0 + wn + nt * 16 + l16;
#pragma unroll
        for (int r = 0; r < 4; ++r)
          C[(row + r) * N + col] = (_Float16)(acc[mt][nt][r] * sc);
      }
    }
  } else if (MODE == 4) {
    if (n0 < INNER) {  // K half: row-major [M, INNER]
      _Float16* C = (_Float16*)Cout;
#pragma unroll
      for (int mt = 0; mt < 4; ++mt) {
        const size_t row = m0 + wm + mt * 16 + quad * 4;
#pragma unroll
        for (int nt = 0; nt < 4; ++nt) {
          const size_t col = n0 + wn + nt * 16 + l16;
#pragma unroll
          for (int r = 0; r < 4; ++r)
            C[(row + r) * INNER + col] = (_Float16)acc[mt][nt][r];
        }
      }
    } else {  // V half: scatter to vT[b][h][d][kv]
      _Float16* C = (_Float16*)Cout2;
      const int b = (int)(m0 >> 10);
#pragma unroll
      for (int mt = 0; mt < 4; ++mt) {
        const int kvb = (int)(m0 & 1023) + wm + mt * 16 + quad * 4;
#pragma unroll
        for (int nt = 0; nt < 4; ++nt) {
          const int col = (int)(n0 - INNER + wn + nt * 16 + l16);
          const int h = col >> 6, d = col & 63;
          half4v pk;
#pragma unroll
          for (int r = 0; r < 4; ++r) pk[r] = (_Float16)acc[mt][nt][r];
          *(half4v*)(C + (size_t)((b * NH + h) * DH + d) * SKV + kvb) = pk;
        }
      }
    }
  }
}

// ---------------------------------------------------------------- fused projections
// (r15-green, unchanged.) Q-proj (512) + KV-proj (256) in one 768-block launch.
// XCD-local mapping; 48 KB ring -> 3 blocks/CU; 768 = exact 3/CU, zero tail.
__global__ __launch_bounds__(256) void proj_fused(const _Float16* __restrict__ xh,
                                                  const _Float16* __restrict__ ctxh,
                                                  const _Float16* __restrict__ wqt,
                                                  const _Float16* __restrict__ wkvt,
                                                  _Float16* __restrict__ qh,
                                                  _Float16* __restrict__ kh,
                                                  _Float16* __restrict__ vth) {
  __shared__ _Float16 As16[3 * 128 * 32];
  __shared__ _Float16 Bs[3 * 128 * 32];
  const int b = blockIdx.x;
  const int xcd = b & 7, j = b >> 3;
  const int seg = j % 3;
  if (seg == 2) {  // KV: M=4096, N=1024 (k|v), K=768; stripes 0..31, n 0..7
    const int jkv = j / 3;  // 0..31
    gemm_body<4, CD, 2 * INNER>(ctxh, wkvt, kh, vth,
                                jkv & 7, xcd * 4 + (jkv >> 3), As16, Bs);
  } else {  // Q: M=16384, N=512, K=1024 (scale folded); stripes 0..127, n 0..3
    const int jq = (j / 3) * 2 + seg;  // 0..63
    gemm_body<3, QD, INNER>(xh, wqt, qh, nullptr,
                            jq & 3, xcd * 16 + (jq >> 2), As16, Bs);
  }
}

// ---------------------------------------------------------------- output projection
// THIS ROUND: 256x128 tile, 8 waves (512 threads, 4m x 2n of 64x64), BK=32, ring-3.
// Mechanism (7th GEMM theory): all prior schedule changes were null because the
// step time is pinned by VMEM-instruction issue (global_load_lds occupies the TA
// per-lane: ~48 wave-instrs/CU/step before). Bigger M-tile amortizes: staged bytes
// per output element drop 25% (24 KB/step for 2x the output area vs 16 KB for 1x;
// 3 GLD16/thread vs 4). LDS = 3 x (16K A + 8K B) = 72 KB -> 2 blocks/CU; grid
// 512 = exactly 2/CU, zero tail, 16 waves/CU (same as before). Swizzle keys
// unchanged: (row>>1)&3 is invariant under +64/+128-row offsets, so read-side
// quad^r2 carries over verbatim. XCD-local: xcd owns stripes [xcd*8, xcd*8+8).
// vmcnt(3): one 3-load stage in flight (prologue issues 6; wait tile t -> 3 left).
__global__ __launch_bounds__(512) void gemm_out(const _Float16* __restrict__ A,
                                                const _Float16* __restrict__ Bt,
                                                float* __restrict__ Cout,
                                                const float* __restrict__ bias) {
  constexpr int K = INNER;  // 512
  constexpr int N = QD;     // 1024
  __shared__ _Float16 As16[3 * 256 * 32];  // 48 KB
  __shared__ _Float16 Bs[3 * 128 * 32];    // 24 KB
  const int tid = threadIdx.x;
  const int wave = tid >> 6, lane = tid & 63;
  const int quad = lane >> 4, l16 = lane & 15;
  const int wm = (wave >> 1) * 64, wn = (wave & 1) * 64;  // wm 0..192, wn 0..64
  const int b = blockIdx.x;
  const int xcd = b & 7, i = b >> 3;  // i: 0..63
  const int bx = i & 7, by = xcd * 8 + (i >> 3);
  const size_t n0 = (size_t)bx * 128, m0 = (size_t)by * 256;

  floatx4 acc[4][4] = {};

  // staging: 512 threads; A rows tid>>2 (+128 for 2nd GLD16), B rows tid>>2.
  // pre-swizzled source blk ^= (row>>1)&3 (key invariant under +128).
  const int r4 = tid >> 2, b4 = (tid & 3) ^ ((r4 >> 1) & 3);
  const _Float16* ag = A + (m0 + r4) * (size_t)K + b4 * 8;
  const _Float16* bg = Bt + (n0 + r4) * (size_t)K + b4 * 8;

#define GSTAGE2(bi, k0)                                                    \
  do {                                                                     \
    GLD16(ag + (k0), As16 + (bi)*8192 + tid * 8);                          \
    GLD16(ag + (k0) + (size_t)128 * K, As16 + (bi)*8192 + tid * 8 + 4096); \
    GLD16(bg + (k0), Bs + (bi)*4096 + tid * 8);                            \
  } while (0)

  constexpr int NT = K / 32;  // 16
  GSTAGE2(0, 0);
  GSTAGE2(1, 32);
  int cb = 0;
#pragma unroll 2
  for (int t = 0; t < NT; ++t) {
    if (t + 1 < NT)
      asm volatile("s_waitcnt vmcnt(3)" ::: "memory");  // tile t landed; t+1 flying
    else
      asm volatile("s_waitcnt vmcnt(0)" ::: "memory");  // final tile
    __builtin_amdgcn_sched_barrier(0);
    __builtin_amdgcn_s_barrier();  // tile t visible; buf (t+2)%3 free
    __builtin_amdgcn_sched_barrier(0);
    if (t + 2 < NT) {
      int nb = cb + 2; if (nb >= 3) nb -= 3;
      GSTAGE2(nb, (t + 2) * 32);
    }
    const _Float16* as = As16 + cb * 8192;
    const _Float16* bs = Bs + cb * 4096;

    const int r2 = (l16 >> 1) & 3;
    half8 af[4], bf[4];
#pragma unroll
    for (int mt = 0; mt < 4; ++mt)
      af[mt] = *(const half8*)(as + (wm + mt * 16 + l16) * 32 + (quad ^ r2) * 8);
#pragma unroll
    for (int nt = 0; nt < 4; ++nt)
      bf[nt] = *(const half8*)(bs + (wn + nt * 16 + l16) * 32 + (quad ^ r2) * 8);
    __builtin_amdgcn_s_setprio(1);
#pragma unroll
    for (int mt = 0; mt < 4; ++mt)
#pragma unroll
      for (int nt = 0; nt < 4; ++nt)
        acc[mt][nt] = MFMA16(af[mt], bf[nt], acc[mt][nt]);
    __builtin_amdgcn_s_setprio(0);
    cb = (cb == 2) ? 0 : cb + 1;
  }
#undef GSTAGE2

  // epilogue: fp32 + bias (green form; row covers m0..m0+255 via wm 0..192)
#pragma unroll
  for (int mt = 0; mt < 4; ++mt) {
    const size_t row = m0 + wm + mt * 16 + quad * 4;
#pragma unroll
    for (int nt = 0; nt < 4; ++nt) {
      const size_t col = n0 + wn + nt * 16 + l16;
      const float bb = bias[col];
#pragma unroll
      for (int r = 0; r < 4; ++r)
        Cout[(row + r) * N + col] = acc[mt][nt][r] + bb;
    }
  }
}

// ---------------------------------------------------------------- flash attention v8
// (byte-identical to r14/r15-green.) 32x32x16 MFMA. Swapped QK^T (S^T = K·Q^T): lane
// owns one q-row, softmax lane-local; P->PV-A transpose = 4 permlane32_swap;
// row-sums via ones-MFMA (same layout as o -> lane-local normalize). KV-tile 64,
// double-buffered LDS, one barrier per tile, prefetch-before-compute. XOR-swizzled
// tiles (blk ^= row&7) with pre-swizzled global source. Grid 1024, XCD swizzle.
// exp path: __builtin_exp2f ONLY (amdgcn builtin and raw asm both red r7/r9 —
// mechanism unresolved, change banned). No setprio (A/B: +3us, lockstep waves).
__global__ __launch_bounds__(256, 4) void flash_attn8(const _Float16* __restrict__ Q,
                                                      const _Float16* __restrict__ Kp,
                                                      const _Float16* __restrict__ Vt,
                                                      _Float16* __restrict__ O) {
  __shared__ _Float16 Ksb[2 * 64 * 64];  // [buf][kv64][d64], 16B-blk XOR by kv&7
  __shared__ _Float16 Vsb[2 * 64 * 64];  // [buf][d64][kv64], 16B-blk XOR by d&7
  const int tid = threadIdx.x;
  const int wave = tid >> 6, lane = tid & 63;
  const int l31 = lane & 31, hi = lane >> 5, x7 = lane & 7;

  // XCD-aware swizzle: 1024 blocks % 8 == 0 -> bijective chunked remap
  const int flat = blockIdx.x;
  const int nf = (flat & 7) * 128 + (flat >> 3);
  const int qblk = nf & 31, bh = nf >> 5;
  const int b = bh >> 3, h = bh & 7;

  const size_t qrow0 = (size_t)b * SQ + qblk * 128 + wave * 32;
  const _Float16* qptr = Q + qrow0 * INNER + h * DH;
  const _Float16* kbase = Kp + (size_t)b * SKV * INNER + h * DH;
  const _Float16* vbase = Vt + (size_t)bh * DH * SKV;

  // staging: linear LDS dest (tid*16B), pre-swizzled global src (blk ^= row&7)
  const int kr = tid >> 3;
  const int kb = (tid & 7) ^ (kr & 7);
  const _Float16* kg = kbase + (size_t)kr * INNER + kb * 8;
  const _Float16* vg = vbase + (size_t)kr * SKV + kb * 8;

#define STAGE_KV(bi, tt)                                                        \
  do {                                                                          \
    _Float16* _kl = Ksb + (bi) * 4096 + tid * 8;                                \
    _Float16* _vl = Vsb + (bi) * 4096 + tid * 8;                                \
    GLD16(kg + (size_t)((tt) * 64) * INNER, _kl);                               \
    GLD16(kg + (size_t)((tt) * 64 + 32) * INNER, _kl + 2048);                   \
    GLD16(vg + (tt) * 64, _vl);                                                 \
    GLD16(vg + (size_t)32 * SKV + (tt) * 64, _vl + 2048);                       \
  } while (0)

  half8 aq[4];
#pragma unroll
  for (int i = 0; i < 4; ++i)
    aq[i] = *(const half8*)(qptr + (size_t)l31 * INNER + i * 16 + hi * 8);

  int koff[4], voffB[4];
#pragma unroll
  for (int i = 0; i < 4; ++i)
    koff[i] = l31 * 64 + (((i * 2 + hi) ^ x7) << 3);
#pragma unroll
  for (int j = 0; j < 4; ++j)
    voffB[j] = l31 * 64 + (((j * 2 + hi) ^ x7) << 3);

  half8 ones;
#pragma unroll
  for (int j = 0; j < 8; ++j) ones[j] = (_Float16)1.0f;

  f32x16 o0 = {}, o1 = {}, osum = {};

  STAGE_KV(0, 0);

  for (int t = 0; t < SKV / 64; ++t) {
    __syncthreads();
    if (t < SKV / 64 - 1) STAGE_KV((t + 1) & 1, t + 1);
    const _Float16* ks = Ksb + (t & 1) * 4096;
    const _Float16* vs = Vsb + (t & 1) * 4096;

#pragma unroll
    for (int c2 = 0; c2 < 2; ++c2) {
      half8 ak[4];
#pragma unroll
      for (int i = 0; i < 4; ++i)
        ak[i] = *(const half8*)(ks + c2 * 2048 + koff[i]);

      f32x16 st = {};
#pragma unroll
      for (int i = 0; i < 4; ++i) st = MFMA32(ak[i], aq[i], st);

      unsigned w[8];
#pragma unroll
      for (int j = 0; j < 8; ++j) {
        float plo = __builtin_exp2f(st[2 * j]);
        float phi = __builtin_exp2f(st[2 * j + 1]);
        w[j] = __builtin_bit_cast(unsigned, __builtin_amdgcn_cvt_pkrtz(plo, phi));
      }
      PLSWAP(w[0], w[2]);
      PLSWAP(w[1], w[3]);
      PLSWAP(w[4], w[6]);
      PLSWAP(w[5], w[7]);
      uint4v u0 = {w[0], w[1], w[2], w[3]};
      uint4v u1 = {w[4], w[5], w[6], w[7]};
      half8 A0 = __builtin_bit_cast(half8, u0);
      half8 A1 = __builtin_bit_cast(half8, u1);

      osum = MFMA32(A0, ones, osum);
      osum = MFMA32(A1, ones, osum);

      {
        half8 bv00 = *(const half8*)(vs + 0 * 2048 + voffB[c2 * 2 + 0]);
        half8 bv10 = *(const half8*)(vs + 1 * 2048 + voffB[c2 * 2 + 0]);
        o0 = MFMA32(A0, bv00, o0);
        o1 = MFMA32(A0, bv10, o1);
        half8 bv01 = *(const half8*)(vs + 0 * 2048 + voffB[c2 * 2 + 1]);
        half8 bv11 = *(const half8*)(vs + 1 * 2048 + voffB[c2 * 2 + 1]);
        o0 = MFMA32(A1, bv01, o0);
        o1 = MFMA32(A1, bv11, o1);
      }
    }
  }

  float inv16[16];
#pragma unroll
  for (int r = 0; r < 16; ++r) inv16[r] = 1.0f / osum[r];

  _Float16* op = O + qrow0 * INNER + h * DH;
#pragma unroll
  for (int r = 0; r < 16; ++r) {
    const int q = (r & 3) + 8 * (r >> 2) + 4 * hi;
    op[(size_t)q * INNER + l31] = (_Float16)(o0[r] * inv16[r]);
    op[(size_t)q * INNER + 32 + l31] = (_Float16)(o1[r] * inv16[r]);
  }
#undef STAGE_KV
}

// ---------------------------------------------------------------- launcher
extern "C" void kernel_launch(void* const* d_in, const int* in_sizes, int n_in,
                              void* d_out, int out_size, void* d_ws, size_t ws_size,
                              hipStream_t stream) {
  const float* x   = (const float*)d_in[0];
  const float* ctx = (const float*)d_in[1];
  const float* Wq  = (const float*)d_in[2];
  const float* Wk  = (const float*)d_in[3];
  const float* Wv  = (const float*)d_in[4];
  const float* Wo  = (const float*)d_in[5];
  const float* bo  = (const float*)d_in[6];
  float* out = (float*)d_out;

  const size_t NX = (size_t)BATCH * SQ * QD;   // 16.7M
  const size_t NC = (size_t)BATCH * SKV * CD;  // 3.1M

  _Float16* ws = (_Float16*)d_ws;
  _Float16* xh   = ws;                                   // [16384,1024] fp16
  _Float16* ctxh = xh + NX;                              // [4096,768]
  _Float16* wqt  = ctxh + NC;                            // [512,1024]
  _Float16* wkvt = wqt + (size_t)INNER * QD;             // [1024,768] (k rows, then v)
  _Float16* wot  = wkvt + (size_t)2 * INNER * CD;        // [1024,512]
  _Float16* qh   = wot + (size_t)QD * INNER;             // [16384,512]
  _Float16* kh   = qh + (size_t)BATCH * SQ * INNER;      // [4096,512]
  _Float16* vth  = kh + (size_t)BATCH * SKV * INNER;     // [4,8,64,1024]
  _Float16* aoh  = xh;  // alias: xh dead after proj_fused; aoh (8.4M) fits in NX

  // cast (9728 blocks) + weight transposes (4096 blocks) in one launch
  prep<<<dim3((unsigned)((NX + NC) / 2048) + 4096), 256, 0, stream>>>(
      x, ctx, Wq, Wk, Wv, Wo, xh, ctxh, wqt, wkvt, wot);

  // fused Q + KV projections (768 blocks = exact 3/CU, XCD-local, fp16 A, 3-ring)
  proj_fused<<<dim3(768), 256, 0, stream>>>(xh, ctxh, wqt, wkvt, qh, kh, vth);

  // attention (1024 blocks, zero tail)
  flash_attn8<<<dim3(BATCH * NH * SQ / 128), 256, 0, stream>>>(qh, kh, vth, aoh);

  // output projection + bias, fp32 out (512 blocks x 512 thr = exact 2/CU, 256x128)
  gemm_out<<<dim3(512), 512, 0, stream>>>(aoh, wot, out, bo);
}